// Round 3
// baseline (607.555 us; speedup 1.0000x reference)
//
#include <hip/hip_runtime.h>

#define NN 50000
#define NE 800000
#define ET (NE + NN)
#define SLOPE 0.2f
#define GEPS 1e-16f
#define NB 196  // (NN+255)/256

// ---------------- CSR build ----------------
__global__ __launch_bounds__(256) void hist_kernel(const int* __restrict__ dst,
                                                   int* __restrict__ deg) {
  int i = blockIdx.x * 256 + threadIdx.x;
  if (i >= ET) return;
  int d = (i < NE) ? dst[i] : (i - NE);
  atomicAdd(&deg[d], 1);
}

__global__ __launch_bounds__(256) void part_kernel(const int* __restrict__ deg,
                                                   int* __restrict__ bsum) {
  __shared__ int lds[256];
  int t = threadIdx.x;
  int i = blockIdx.x * 256 + t;
  lds[t] = (i < NN) ? deg[i] : 0;
  __syncthreads();
  for (int off = 128; off > 0; off >>= 1) {
    if (t < off) lds[t] += lds[t + off];
    __syncthreads();
  }
  if (t == 0) bsum[blockIdx.x] = lds[0];
}

__global__ __launch_bounds__(256) void bscan_kernel(const int* __restrict__ bsum,
                                                    int* __restrict__ boff) {
  __shared__ int lds[256];
  int t = threadIdx.x;
  int v = (t < NB) ? bsum[t] : 0;
  lds[t] = v;
  __syncthreads();
  for (int off = 1; off < 256; off <<= 1) {
    int u = (t >= off) ? lds[t - off] : 0;
    __syncthreads();
    lds[t] += u;
    __syncthreads();
  }
  if (t < NB) boff[t] = lds[t] - v;
}

__global__ __launch_bounds__(256) void rowptr_kernel(const int* __restrict__ deg,
                                                     const int* __restrict__ boff,
                                                     int* __restrict__ rowptr,
                                                     int* __restrict__ cursor) {
  __shared__ int lds[256];
  int t = threadIdx.x;
  int i = blockIdx.x * 256 + t;
  int v = (i < NN) ? deg[i] : 0;
  lds[t] = v;
  __syncthreads();
  for (int off = 1; off < 256; off <<= 1) {
    int u = (t >= off) ? lds[t - off] : 0;
    __syncthreads();
    lds[t] += u;
    __syncthreads();
  }
  if (i < NN) {
    int excl = boff[blockIdx.x] + lds[t] - v;
    rowptr[i] = excl;
    cursor[i] = excl;
    if (i == NN - 1) rowptr[NN] = excl + v;
  }
}

__global__ __launch_bounds__(256) void scatter_kernel(const int* __restrict__ srcA,
                                                      const int* __restrict__ dstA,
                                                      int* __restrict__ cursor,
                                                      int* __restrict__ csr_src) {
  int i = blockIdx.x * 256 + threadIdx.x;
  if (i >= ET) return;
  int s, d;
  if (i < NE) { s = srcA[i]; d = dstA[i]; } else { s = d = i - NE; }
  int pos = atomicAdd(&cursor[d], 1);
  csr_src[pos] = s;
}

// ---- GEMM + fused attention dots: H = A(N x 128) @ B(128 x NC) ----
// BK=32 chunks; A[64][36] (pad, 16B-aligned rows) + B[32][NC] in LDS (~25KB).
// Epilogue: per-row att_src/att_dst dots via shfl_xor within head tx-group.
template <int NC>
__global__ __launch_bounds__(256) void gemm_att_kernel(
    const float* __restrict__ A, const float* __restrict__ B,
    const float* __restrict__ atts, const float* __restrict__ attd,
    float* __restrict__ H, float* __restrict__ a_s, float* __restrict__ a_d,
    int N) {
  constexpr int K = 128, BM = 64, BK = 32, BKP = BK + 4;
  constexpr int TX = NC / 4;      // 32 (NC=128) or 16 (NC=64)
  constexpr int TY = 256 / TX;    // 8 or 16
  constexpr int RPT = BM / TY;    // 8 or 4
  constexpr int AF4 = BM * BK / (4 * 256);  // 2
  constexpr int BF4 = BK * NC / (4 * 256);  // 4 or 2
  __shared__ float Asl[BM][BKP];
  __shared__ float Bsl[BK][NC];
  const int tid = threadIdx.x;
  const int tx = tid % TX, ty = tid / TX;
  const int row0 = blockIdx.x * BM;
  float acc[RPT][4];
#pragma unroll
  for (int i = 0; i < RPT; ++i)
    acc[i][0] = acc[i][1] = acc[i][2] = acc[i][3] = 0.f;

  for (int k0 = 0; k0 < K; k0 += BK) {
    if (k0) __syncthreads();
#pragma unroll
    for (int j = 0; j < AF4; ++j) {
      int idx = j * 256 + tid;
      int r = idx >> 3, kq = (idx & 7) << 2;
      int gr = row0 + r;
      float4 v = make_float4(0.f, 0.f, 0.f, 0.f);
      if (gr < N) v = *(const float4*)(A + (size_t)gr * K + k0 + kq);
      *(float4*)&Asl[r][kq] = v;
    }
#pragma unroll
    for (int j = 0; j < BF4; ++j) {
      int idx = j * 256 + tid;
      int kr = idx / (NC / 4), c4 = (idx % (NC / 4)) << 2;
      *(float4*)&Bsl[kr][c4] = *(const float4*)(B + (size_t)(k0 + kr) * NC + c4);
    }
    __syncthreads();
    for (int kk = 0; kk < BK; kk += 4) {
      float4 b0 = *(const float4*)&Bsl[kk + 0][tx * 4];
      float4 b1 = *(const float4*)&Bsl[kk + 1][tx * 4];
      float4 b2 = *(const float4*)&Bsl[kk + 2][tx * 4];
      float4 b3 = *(const float4*)&Bsl[kk + 3][tx * 4];
#pragma unroll
      for (int i = 0; i < RPT; ++i) {
        float4 a = *(const float4*)&Asl[ty * RPT + i][kk];
        acc[i][0] += a.x * b0.x + a.y * b1.x + a.z * b2.x + a.w * b3.x;
        acc[i][1] += a.x * b0.y + a.y * b1.y + a.z * b2.y + a.w * b3.y;
        acc[i][2] += a.x * b0.z + a.y * b1.z + a.z * b2.z + a.w * b3.z;
        acc[i][3] += a.x * b0.w + a.y * b1.w + a.z * b2.w + a.w * b3.w;
      }
    }
  }
  // att weights for this thread's 4 columns (flat layout matches [H][C])
  float asl[4], adl[4];
#pragma unroll
  for (int q = 0; q < 4; ++q) {
    asl[q] = atts[tx * 4 + q];
    adl[q] = attd[tx * 4 + q];
  }
#pragma unroll
  for (int i = 0; i < RPT; ++i) {
    int gr = row0 + ty * RPT + i;
    float sp = acc[i][0] * asl[0] + acc[i][1] * asl[1] + acc[i][2] * asl[2] +
               acc[i][3] * asl[3];
    float dp = acc[i][0] * adl[0] + acc[i][1] * adl[1] + acc[i][2] * adl[2] +
               acc[i][3] * adl[3];
    if (NC == 128) {  // 4 heads x 32 ch: reduce over 8-lane tx groups
      sp += __shfl_xor(sp, 1); sp += __shfl_xor(sp, 2); sp += __shfl_xor(sp, 4);
      dp += __shfl_xor(dp, 1); dp += __shfl_xor(dp, 2); dp += __shfl_xor(dp, 4);
      if ((tx & 7) == 0 && gr < N) {
        int hd = tx >> 3;
        a_s[gr * 4 + hd] = sp;
        a_d[gr * 4 + hd] = dp;
      }
    } else {  // 1 head x 64 ch: reduce over 16-lane tx group
      sp += __shfl_xor(sp, 1); sp += __shfl_xor(sp, 2);
      sp += __shfl_xor(sp, 4); sp += __shfl_xor(sp, 8);
      dp += __shfl_xor(dp, 1); dp += __shfl_xor(dp, 2);
      dp += __shfl_xor(dp, 4); dp += __shfl_xor(dp, 8);
      if (tx == 0 && gr < N) {
        a_s[gr] = sp;
        a_d[gr] = dp;
      }
    }
    if (gr < N)
      *(float4*)(H + (size_t)gr * NC + tx * 4) =
          make_float4(acc[i][0], acc[i][1], acc[i][2], acc[i][3]);
  }
}

// ---------------- layer-1 aggregation: wave/node, 4 edges per iter ----------------
__global__ __launch_bounds__(256) void gat1_kernel(const int* __restrict__ rowptr,
                                                   const int* __restrict__ csr_src,
                                                   const float* __restrict__ h1,
                                                   const float* __restrict__ as1,
                                                   const float* __restrict__ ad1,
                                                   const float* __restrict__ b1,
                                                   float* __restrict__ out1, int N) {
  int n = (blockIdx.x * 256 + threadIdx.x) >> 6;
  int l = threadIdx.x & 63;
  if (n >= N) return;
  int start = rowptr[n], end = rowptr[n + 1];
  int c = l & 31, half = l >> 5;
  int hB = c >> 3;
  float ad_b = ad1[n * 4 + hB];
  float ax = 0.f, ay = 0.f, az = 0.f, aw = 0.f, z = 0.f;
  int e = start + half;
  for (; e + 2 < end; e += 4) {
    int s0 = csr_src[e];
    int s1 = csr_src[e + 2];
    float a0 = as1[s0 * 4 + hB] + ad_b;
    float a1 = as1[s1 * 4 + hB] + ad_b;
    float4 g0 = *(const float4*)(h1 + (size_t)s0 * 128 + 4 * c);
    float4 g1 = *(const float4*)(h1 + (size_t)s1 * 128 + 4 * c);
    a0 = (a0 > 0.f) ? a0 : SLOPE * a0;
    a1 = (a1 > 0.f) ? a1 : SLOPE * a1;
    float w0 = __expf(a0), w1 = __expf(a1);
    ax += w0 * g0.x + w1 * g1.x;
    ay += w0 * g0.y + w1 * g1.y;
    az += w0 * g0.z + w1 * g1.z;
    aw += w0 * g0.w + w1 * g1.w;
    z += w0 + w1;
  }
  for (; e < end; e += 2) {
    int s = csr_src[e];
    float a = as1[s * 4 + hB] + ad_b;
    a = (a > 0.f) ? a : SLOPE * a;
    float w = __expf(a);
    float4 g = *(const float4*)(h1 + (size_t)s * 128 + 4 * c);
    ax += w * g.x; ay += w * g.y; az += w * g.z; aw += w * g.w;
    z += w;
  }
  ax += __shfl_xor(ax, 32);
  ay += __shfl_xor(ay, 32);
  az += __shfl_xor(az, 32);
  aw += __shfl_xor(aw, 32);
  z += __shfl_xor(z, 32);
  if (half == 0) {
    float inv = 1.f / (z + GEPS);
    float4 bb = *(const float4*)(b1 + 4 * c);
    float4 o;
    o.x = fmaxf(ax * inv + bb.x, 0.f);
    o.y = fmaxf(ay * inv + bb.y, 0.f);
    o.z = fmaxf(az * inv + bb.z, 0.f);
    o.w = fmaxf(aw * inv + bb.w, 0.f);
    *(float4*)(out1 + (size_t)n * 128 + 4 * c) = o;
  }
}

// ---------------- layer-2 aggregation: wave/node, 8 edges per iter ----------------
__global__ __launch_bounds__(256) void gat2_kernel(const int* __restrict__ rowptr,
                                                   const int* __restrict__ csr_src,
                                                   const float* __restrict__ h2,
                                                   const float* __restrict__ as2,
                                                   const float* __restrict__ ad2,
                                                   const float* __restrict__ b2,
                                                   float* __restrict__ out, int N) {
  int n = (blockIdx.x * 256 + threadIdx.x) >> 6;
  int l = threadIdx.x & 63;
  if (n >= N) return;
  int start = rowptr[n], end = rowptr[n + 1];
  int c = l & 15, q = l >> 4;
  float ad = ad2[n];
  float ax = 0.f, ay = 0.f, az = 0.f, aw = 0.f, z = 0.f;
  int e = start + q;
  for (; e + 4 < end; e += 8) {
    int s0 = csr_src[e];
    int s1 = csr_src[e + 4];
    float a0 = as2[s0] + ad;
    float a1 = as2[s1] + ad;
    float4 g0 = *(const float4*)(h2 + (size_t)s0 * 64 + 4 * c);
    float4 g1 = *(const float4*)(h2 + (size_t)s1 * 64 + 4 * c);
    a0 = (a0 > 0.f) ? a0 : SLOPE * a0;
    a1 = (a1 > 0.f) ? a1 : SLOPE * a1;
    float w0 = __expf(a0), w1 = __expf(a1);
    ax += w0 * g0.x + w1 * g1.x;
    ay += w0 * g0.y + w1 * g1.y;
    az += w0 * g0.z + w1 * g1.z;
    aw += w0 * g0.w + w1 * g1.w;
    z += w0 + w1;
  }
  for (; e < end; e += 4) {
    int s = csr_src[e];
    float a = as2[s] + ad;
    a = (a > 0.f) ? a : SLOPE * a;
    float w = __expf(a);
    float4 g = *(const float4*)(h2 + (size_t)s * 64 + 4 * c);
    ax += w * g.x; ay += w * g.y; az += w * g.z; aw += w * g.w;
    z += w;
  }
  ax += __shfl_xor(ax, 16); ax += __shfl_xor(ax, 32);
  ay += __shfl_xor(ay, 16); ay += __shfl_xor(ay, 32);
  az += __shfl_xor(az, 16); az += __shfl_xor(az, 32);
  aw += __shfl_xor(aw, 16); aw += __shfl_xor(aw, 32);
  z += __shfl_xor(z, 16);  z += __shfl_xor(z, 32);
  if (q == 0) {
    float inv = 1.f / (z + GEPS);
    float4 bb = *(const float4*)(b2 + 4 * c);
    float4 o;
    o.x = fmaxf(ax * inv + bb.x, 0.f);
    o.y = fmaxf(ay * inv + bb.y, 0.f);
    o.z = fmaxf(az * inv + bb.z, 0.f);
    o.w = fmaxf(aw * inv + bb.w, 0.f);
    *(float4*)(out + (size_t)n * 64 + 4 * c) = o;
  }
}

extern "C" void kernel_launch(void* const* d_in, const int* in_sizes, int n_in,
                              void* d_out, int out_size, void* d_ws, size_t ws_size,
                              hipStream_t stream) {
  const float* x = (const float*)d_in[0];
  const int* ei = (const int*)d_in[1];
  const float* W1 = (const float*)d_in[2];
  const float* att_s1 = (const float*)d_in[3];
  const float* att_d1 = (const float*)d_in[4];
  const float* b1 = (const float*)d_in[5];
  const float* W2 = (const float*)d_in[6];
  const float* att_s2 = (const float*)d_in[7];
  const float* att_d2 = (const float*)d_in[8];
  const float* b2 = (const float*)d_in[9];
  float* out = (float*)d_out;

  char* ws = (char*)d_ws;
  size_t off = 0;
  auto alloc = [&](size_t bytes) {
    off = (off + 255) & ~(size_t)255;
    void* p = ws + off;
    off += bytes;
    return p;
  };
  int* deg = (int*)alloc((NN + 1) * sizeof(int));
  int* rowptr = (int*)alloc((NN + 1) * sizeof(int));
  int* cursor = (int*)alloc((size_t)NN * sizeof(int));
  int* bsum = (int*)alloc(NB * sizeof(int));
  int* boff = (int*)alloc(NB * sizeof(int));
  int* csr_src = (int*)alloc((size_t)ET * sizeof(int));
  float* h1 = (float*)alloc((size_t)NN * 128 * sizeof(float));
  float* as1 = (float*)alloc((size_t)NN * 4 * sizeof(float));
  float* ad1 = (float*)alloc((size_t)NN * 4 * sizeof(float));
  float* out1 = (float*)alloc((size_t)NN * 128 * sizeof(float));
  float* hh2 = h1;   // layer-2 features reuse h1 (dead after gat1)
  float* as2 = as1;
  float* ad2 = ad1;

  const int* src = ei;
  const int* dst = ei + NE;

  hipMemsetAsync(deg, 0, (NN + 1) * sizeof(int), stream);
  int ebks = (ET + 255) / 256;
  hipLaunchKernelGGL(hist_kernel, dim3(ebks), dim3(256), 0, stream, dst, deg);
  hipLaunchKernelGGL(part_kernel, dim3(NB), dim3(256), 0, stream, deg, bsum);
  hipLaunchKernelGGL(bscan_kernel, dim3(1), dim3(256), 0, stream, bsum, boff);
  hipLaunchKernelGGL(rowptr_kernel, dim3(NB), dim3(256), 0, stream, deg, boff, rowptr,
                     cursor);
  hipLaunchKernelGGL(scatter_kernel, dim3(ebks), dim3(256), 0, stream, src, dst, cursor,
                     csr_src);

  hipLaunchKernelGGL((gemm_att_kernel<128>), dim3((NN + 63) / 64), dim3(256), 0, stream,
                     x, W1, att_s1, att_d1, h1, as1, ad1, NN);
  hipLaunchKernelGGL(gat1_kernel, dim3((NN + 3) / 4), dim3(256), 0, stream, rowptr,
                     csr_src, h1, as1, ad1, b1, out1, NN);

  hipLaunchKernelGGL((gemm_att_kernel<64>), dim3((NN + 63) / 64), dim3(256), 0, stream,
                     out1, W2, att_s2, att_d2, hh2, as2, ad2, NN);
  hipLaunchKernelGGL(gat2_kernel, dim3((NN + 3) / 4), dim3(256), 0, stream, rowptr,
                     csr_src, hh2, as2, ad2, b2, out, NN);
}

// Round 4
// 286.202 us; speedup vs baseline: 2.1228x; 2.1228x over previous
//
#include <hip/hip_runtime.h>

#define NN 50000
#define NE 800000
#define ET (NE + NN)
#define SLOPE 0.2f
#define GEPS 1e-16f
#define NB 196  // (NN+255)/256

// ---------------- CSR build ----------------
__global__ __launch_bounds__(256) void hist_kernel(const int* __restrict__ dst,
                                                   int* __restrict__ deg) {
  int i = blockIdx.x * 256 + threadIdx.x;
  if (i >= ET) return;
  int d = (i < NE) ? dst[i] : (i - NE);
  atomicAdd(&deg[d], 1);
}

__global__ __launch_bounds__(256) void part_kernel(const int* __restrict__ deg,
                                                   int* __restrict__ bsum) {
  __shared__ int lds[256];
  int t = threadIdx.x;
  int i = blockIdx.x * 256 + t;
  lds[t] = (i < NN) ? deg[i] : 0;
  __syncthreads();
  for (int off = 128; off > 0; off >>= 1) {
    if (t < off) lds[t] += lds[t + off];
    __syncthreads();
  }
  if (t == 0) bsum[blockIdx.x] = lds[0];
}

__global__ __launch_bounds__(256) void bscan_kernel(const int* __restrict__ bsum,
                                                    int* __restrict__ boff) {
  __shared__ int lds[256];
  int t = threadIdx.x;
  int v = (t < NB) ? bsum[t] : 0;
  lds[t] = v;
  __syncthreads();
  for (int off = 1; off < 256; off <<= 1) {
    int u = (t >= off) ? lds[t - off] : 0;
    __syncthreads();
    lds[t] += u;
    __syncthreads();
  }
  if (t < NB) boff[t] = lds[t] - v;
}

__global__ __launch_bounds__(256) void rowptr_kernel(const int* __restrict__ deg,
                                                     const int* __restrict__ boff,
                                                     int* __restrict__ rowptr,
                                                     int* __restrict__ cursor) {
  __shared__ int lds[256];
  int t = threadIdx.x;
  int i = blockIdx.x * 256 + t;
  int v = (i < NN) ? deg[i] : 0;
  lds[t] = v;
  __syncthreads();
  for (int off = 1; off < 256; off <<= 1) {
    int u = (t >= off) ? lds[t - off] : 0;
    __syncthreads();
    lds[t] += u;
    __syncthreads();
  }
  if (i < NN) {
    int excl = boff[blockIdx.x] + lds[t] - v;
    rowptr[i] = excl;
    cursor[i] = excl;
    if (i == NN - 1) rowptr[NN] = excl + v;
  }
}

__global__ __launch_bounds__(256) void scatter_kernel(const int* __restrict__ srcA,
                                                      const int* __restrict__ dstA,
                                                      int* __restrict__ cursor,
                                                      int* __restrict__ csr_src) {
  int i = blockIdx.x * 256 + threadIdx.x;
  if (i >= ET) return;
  int s, d;
  if (i < NE) { s = srcA[i]; d = dstA[i]; } else { s = d = i - NE; }
  int pos = atomicAdd(&cursor[d], 1);
  csr_src[pos] = s;
}

// ---- GEMM: H = A(N x 128) @ B(128 x NC), 64x64 tile, full-K LDS ----
// grid = (ceil(N/64), NC/64). LDS = 33.8KB (A) + 32KB (B) -> 2 blocks/CU.
// Thread (tx,ty): tx=tid&15 owns cols col0+tx*4..+3, ty=tid>>4 owns rows
// row0+ty*4..+3. acc[4][4] = 16 VGPRs.
template <int NC>
__global__ __launch_bounds__(256) void gemm_kernel(const float* __restrict__ A,
                                                   const float* __restrict__ B,
                                                   float* __restrict__ H, int N) {
  constexpr int K = 128, BM = 64, BN = 64, KP = K + 4;  // KP=132: 2-way banks
  __shared__ float Asl[BM][KP];
  __shared__ float Bsl[K][BN];
  const int tid = threadIdx.x;
  const int tx = tid & 15, ty = tid >> 4;
  const int row0 = blockIdx.x * BM;
  const int col0 = blockIdx.y * BN;
#pragma unroll
  for (int j = 0; j < 8; ++j) {  // stage A: 2048 float4s
    int idx = j * 256 + tid;
    int r = idx >> 5, c4 = (idx & 31) << 2;
    int gr = row0 + r;
    float4 v = make_float4(0.f, 0.f, 0.f, 0.f);
    if (gr < N) v = *(const float4*)(A + (size_t)gr * K + c4);
    *(float4*)&Asl[r][c4] = v;
  }
#pragma unroll
  for (int j = 0; j < 8; ++j) {  // stage B panel: 2048 float4s
    int idx = j * 256 + tid;
    int kr = idx >> 4, c4 = (idx & 15) << 2;
    *(float4*)&Bsl[kr][c4] = *(const float4*)(B + (size_t)kr * NC + col0 + c4);
  }
  __syncthreads();
  float acc[4][4];
#pragma unroll
  for (int i = 0; i < 4; ++i)
    acc[i][0] = acc[i][1] = acc[i][2] = acc[i][3] = 0.f;
#pragma unroll 2
  for (int k = 0; k < K; k += 4) {
    float4 b0 = *(const float4*)&Bsl[k + 0][tx * 4];
    float4 b1 = *(const float4*)&Bsl[k + 1][tx * 4];
    float4 b2 = *(const float4*)&Bsl[k + 2][tx * 4];
    float4 b3 = *(const float4*)&Bsl[k + 3][tx * 4];
#pragma unroll
    for (int i = 0; i < 4; ++i) {
      float4 a = *(const float4*)&Asl[ty * 4 + i][k];
      acc[i][0] += a.x * b0.x + a.y * b1.x + a.z * b2.x + a.w * b3.x;
      acc[i][1] += a.x * b0.y + a.y * b1.y + a.z * b2.y + a.w * b3.y;
      acc[i][2] += a.x * b0.z + a.y * b1.z + a.z * b2.z + a.w * b3.z;
      acc[i][3] += a.x * b0.w + a.y * b1.w + a.z * b2.w + a.w * b3.w;
    }
  }
#pragma unroll
  for (int i = 0; i < 4; ++i) {
    int gr = row0 + ty * 4 + i;
    if (gr < N)
      *(float4*)(H + (size_t)gr * NC + col0 + tx * 4) =
          make_float4(acc[i][0], acc[i][1], acc[i][2], acc[i][3]);
  }
}

// ---------------- attention dot products ----------------
template <int F, int C>
__global__ __launch_bounds__(256) void att_kernel(const float* __restrict__ Hm,
                                                  const float* __restrict__ att_s,
                                                  const float* __restrict__ att_d,
                                                  float* __restrict__ a_s,
                                                  float* __restrict__ a_d, int N) {
  constexpr int NH = F / C;
  constexpr int PB = 256 / F;
  int n = blockIdx.x * PB + threadIdx.x / F;
  int l = threadIdx.x % F;
  if (n >= N) return;
  float h = Hm[(size_t)n * F + l];
  float vs = h * att_s[l];
  float vd = h * att_d[l];
#pragma unroll
  for (int m = 1; m < C; m <<= 1) {
    vs += __shfl_xor(vs, m);
    vd += __shfl_xor(vd, m);
  }
  if ((l % C) == 0) {
    int hh = l / C;
    a_s[n * NH + hh] = vs;
    a_d[n * NH + hh] = vd;
  }
}

// ---------------- layer-1 aggregation: wave/node, 4 edges per iter ----------------
__global__ __launch_bounds__(256) void gat1_kernel(const int* __restrict__ rowptr,
                                                   const int* __restrict__ csr_src,
                                                   const float* __restrict__ h1,
                                                   const float* __restrict__ as1,
                                                   const float* __restrict__ ad1,
                                                   const float* __restrict__ b1,
                                                   float* __restrict__ out1, int N) {
  int n = (blockIdx.x * 256 + threadIdx.x) >> 6;
  int l = threadIdx.x & 63;
  if (n >= N) return;
  int start = rowptr[n], end = rowptr[n + 1];
  int c = l & 31, half = l >> 5;
  int hB = c >> 3;
  float ad_b = ad1[n * 4 + hB];
  float ax = 0.f, ay = 0.f, az = 0.f, aw = 0.f, z = 0.f;
  int e = start + half;
  for (; e + 2 < end; e += 4) {
    int s0 = csr_src[e];
    int s1 = csr_src[e + 2];
    float a0 = as1[s0 * 4 + hB] + ad_b;
    float a1 = as1[s1 * 4 + hB] + ad_b;
    float4 g0 = *(const float4*)(h1 + (size_t)s0 * 128 + 4 * c);
    float4 g1 = *(const float4*)(h1 + (size_t)s1 * 128 + 4 * c);
    a0 = (a0 > 0.f) ? a0 : SLOPE * a0;
    a1 = (a1 > 0.f) ? a1 : SLOPE * a1;
    float w0 = __expf(a0), w1 = __expf(a1);
    ax += w0 * g0.x + w1 * g1.x;
    ay += w0 * g0.y + w1 * g1.y;
    az += w0 * g0.z + w1 * g1.z;
    aw += w0 * g0.w + w1 * g1.w;
    z += w0 + w1;
  }
  for (; e < end; e += 2) {
    int s = csr_src[e];
    float a = as1[s * 4 + hB] + ad_b;
    a = (a > 0.f) ? a : SLOPE * a;
    float w = __expf(a);
    float4 g = *(const float4*)(h1 + (size_t)s * 128 + 4 * c);
    ax += w * g.x; ay += w * g.y; az += w * g.z; aw += w * g.w;
    z += w;
  }
  ax += __shfl_xor(ax, 32);
  ay += __shfl_xor(ay, 32);
  az += __shfl_xor(az, 32);
  aw += __shfl_xor(aw, 32);
  z += __shfl_xor(z, 32);
  if (half == 0) {
    float inv = 1.f / (z + GEPS);
    float4 bb = *(const float4*)(b1 + 4 * c);
    float4 o;
    o.x = fmaxf(ax * inv + bb.x, 0.f);
    o.y = fmaxf(ay * inv + bb.y, 0.f);
    o.z = fmaxf(az * inv + bb.z, 0.f);
    o.w = fmaxf(aw * inv + bb.w, 0.f);
    *(float4*)(out1 + (size_t)n * 128 + 4 * c) = o;
  }
}

// ---------------- layer-2 aggregation: wave/node, 8 edges per iter ----------------
__global__ __launch_bounds__(256) void gat2_kernel(const int* __restrict__ rowptr,
                                                   const int* __restrict__ csr_src,
                                                   const float* __restrict__ h2,
                                                   const float* __restrict__ as2,
                                                   const float* __restrict__ ad2,
                                                   const float* __restrict__ b2,
                                                   float* __restrict__ out, int N) {
  int n = (blockIdx.x * 256 + threadIdx.x) >> 6;
  int l = threadIdx.x & 63;
  if (n >= N) return;
  int start = rowptr[n], end = rowptr[n + 1];
  int c = l & 15, q = l >> 4;
  float ad = ad2[n];
  float ax = 0.f, ay = 0.f, az = 0.f, aw = 0.f, z = 0.f;
  int e = start + q;
  for (; e + 4 < end; e += 8) {
    int s0 = csr_src[e];
    int s1 = csr_src[e + 4];
    float a0 = as2[s0] + ad;
    float a1 = as2[s1] + ad;
    float4 g0 = *(const float4*)(h2 + (size_t)s0 * 64 + 4 * c);
    float4 g1 = *(const float4*)(h2 + (size_t)s1 * 64 + 4 * c);
    a0 = (a0 > 0.f) ? a0 : SLOPE * a0;
    a1 = (a1 > 0.f) ? a1 : SLOPE * a1;
    float w0 = __expf(a0), w1 = __expf(a1);
    ax += w0 * g0.x + w1 * g1.x;
    ay += w0 * g0.y + w1 * g1.y;
    az += w0 * g0.z + w1 * g1.z;
    aw += w0 * g0.w + w1 * g1.w;
    z += w0 + w1;
  }
  for (; e < end; e += 4) {
    int s = csr_src[e];
    float a = as2[s] + ad;
    a = (a > 0.f) ? a : SLOPE * a;
    float w = __expf(a);
    float4 g = *(const float4*)(h2 + (size_t)s * 64 + 4 * c);
    ax += w * g.x; ay += w * g.y; az += w * g.z; aw += w * g.w;
    z += w;
  }
  ax += __shfl_xor(ax, 16); ax += __shfl_xor(ax, 32);
  ay += __shfl_xor(ay, 16); ay += __shfl_xor(ay, 32);
  az += __shfl_xor(az, 16); az += __shfl_xor(az, 32);
  aw += __shfl_xor(aw, 16); aw += __shfl_xor(aw, 32);
  z += __shfl_xor(z, 16);  z += __shfl_xor(z, 32);
  if (q == 0) {
    float inv = 1.f / (z + GEPS);
    float4 bb = *(const float4*)(b2 + 4 * c);
    float4 o;
    o.x = fmaxf(ax * inv + bb.x, 0.f);
    o.y = fmaxf(ay * inv + bb.y, 0.f);
    o.z = fmaxf(az * inv + bb.z, 0.f);
    o.w = fmaxf(aw * inv + bb.w, 0.f);
    *(float4*)(out + (size_t)n * 64 + 4 * c) = o;
  }
}

extern "C" void kernel_launch(void* const* d_in, const int* in_sizes, int n_in,
                              void* d_out, int out_size, void* d_ws, size_t ws_size,
                              hipStream_t stream) {
  const float* x = (const float*)d_in[0];
  const int* ei = (const int*)d_in[1];
  const float* W1 = (const float*)d_in[2];
  const float* att_s1 = (const float*)d_in[3];
  const float* att_d1 = (const float*)d_in[4];
  const float* b1 = (const float*)d_in[5];
  const float* W2 = (const float*)d_in[6];
  const float* att_s2 = (const float*)d_in[7];
  const float* att_d2 = (const float*)d_in[8];
  const float* b2 = (const float*)d_in[9];
  float* out = (float*)d_out;

  char* ws = (char*)d_ws;
  size_t off = 0;
  auto alloc = [&](size_t bytes) {
    off = (off + 255) & ~(size_t)255;
    void* p = ws + off;
    off += bytes;
    return p;
  };
  int* deg = (int*)alloc((NN + 1) * sizeof(int));
  int* rowptr = (int*)alloc((NN + 1) * sizeof(int));
  int* cursor = (int*)alloc((size_t)NN * sizeof(int));
  int* bsum = (int*)alloc(NB * sizeof(int));
  int* boff = (int*)alloc(NB * sizeof(int));
  int* csr_src = (int*)alloc((size_t)ET * sizeof(int));
  float* h1 = (float*)alloc((size_t)NN * 128 * sizeof(float));
  float* as1 = (float*)alloc((size_t)NN * 4 * sizeof(float));
  float* ad1 = (float*)alloc((size_t)NN * 4 * sizeof(float));
  float* out1 = (float*)alloc((size_t)NN * 128 * sizeof(float));
  float* hh2 = h1;   // layer-2 features reuse h1 (dead after gat1)
  float* as2 = as1;
  float* ad2 = ad1;

  const int* src = ei;
  const int* dst = ei + NE;

  hipMemsetAsync(deg, 0, (NN + 1) * sizeof(int), stream);
  int ebks = (ET + 255) / 256;
  hipLaunchKernelGGL(hist_kernel, dim3(ebks), dim3(256), 0, stream, dst, deg);
  hipLaunchKernelGGL(part_kernel, dim3(NB), dim3(256), 0, stream, deg, bsum);
  hipLaunchKernelGGL(bscan_kernel, dim3(1), dim3(256), 0, stream, bsum, boff);
  hipLaunchKernelGGL(rowptr_kernel, dim3(NB), dim3(256), 0, stream, deg, boff, rowptr,
                     cursor);
  hipLaunchKernelGGL(scatter_kernel, dim3(ebks), dim3(256), 0, stream, src, dst, cursor,
                     csr_src);

  int rbks = (NN + 63) / 64;
  hipLaunchKernelGGL((gemm_kernel<128>), dim3(rbks, 2), dim3(256), 0, stream, x, W1, h1,
                     NN);
  hipLaunchKernelGGL((att_kernel<128, 32>), dim3((NN + 1) / 2), dim3(256), 0, stream,
                     h1, att_s1, att_d1, as1, ad1, NN);
  hipLaunchKernelGGL(gat1_kernel, dim3((NN + 3) / 4), dim3(256), 0, stream, rowptr,
                     csr_src, h1, as1, ad1, b1, out1, NN);

  hipLaunchKernelGGL((gemm_kernel<64>), dim3(rbks, 1), dim3(256), 0, stream, out1, W2,
                     hh2, NN);
  hipLaunchKernelGGL((att_kernel<64, 64>), dim3((NN + 3) / 4), dim3(256), 0, stream,
                     hh2, att_s2, att_d2, as2, ad2, NN);
  hipLaunchKernelGGL(gat2_kernel, dim3((NN + 3) / 4), dim3(256), 0, stream, rowptr,
                     csr_src, hh2, as2, ad2, b2, out, NN);
}

// Round 5
// 241.708 us; speedup vs baseline: 2.5136x; 1.1841x over previous
//
#include <hip/hip_runtime.h>
#include <hip/hip_fp16.h>

#define NN 50000
#define NE 800000
#define ET (NE + NN)
#define SLOPE 0.2f
#define GEPS 1e-16f
#define NB 196  // (NN+255)/256

// ---------------- CSR build ----------------
__global__ __launch_bounds__(256) void hist_kernel(const int* __restrict__ dst,
                                                   int* __restrict__ deg) {
  int i = blockIdx.x * 256 + threadIdx.x;
  if (i >= ET) return;
  int d = (i < NE) ? dst[i] : (i - NE);
  atomicAdd(&deg[d], 1);
}

__global__ __launch_bounds__(256) void part_kernel(const int* __restrict__ deg,
                                                   int* __restrict__ bsum) {
  __shared__ int lds[256];
  int t = threadIdx.x;
  int i = blockIdx.x * 256 + t;
  lds[t] = (i < NN) ? deg[i] : 0;
  __syncthreads();
  for (int off = 128; off > 0; off >>= 1) {
    if (t < off) lds[t] += lds[t + off];
    __syncthreads();
  }
  if (t == 0) bsum[blockIdx.x] = lds[0];
}

__global__ __launch_bounds__(256) void bscan_kernel(const int* __restrict__ bsum,
                                                    int* __restrict__ boff) {
  __shared__ int lds[256];
  int t = threadIdx.x;
  int v = (t < NB) ? bsum[t] : 0;
  lds[t] = v;
  __syncthreads();
  for (int off = 1; off < 256; off <<= 1) {
    int u = (t >= off) ? lds[t - off] : 0;
    __syncthreads();
    lds[t] += u;
    __syncthreads();
  }
  if (t < NB) boff[t] = lds[t] - v;
}

__global__ __launch_bounds__(256) void rowptr_kernel(const int* __restrict__ deg,
                                                     const int* __restrict__ boff,
                                                     int* __restrict__ rowptr,
                                                     int* __restrict__ cursor) {
  __shared__ int lds[256];
  int t = threadIdx.x;
  int i = blockIdx.x * 256 + t;
  int v = (i < NN) ? deg[i] : 0;
  lds[t] = v;
  __syncthreads();
  for (int off = 1; off < 256; off <<= 1) {
    int u = (t >= off) ? lds[t - off] : 0;
    __syncthreads();
    lds[t] += u;
    __syncthreads();
  }
  if (i < NN) {
    int excl = boff[blockIdx.x] + lds[t] - v;
    rowptr[i] = excl;
    cursor[i] = excl;
    if (i == NN - 1) rowptr[NN] = excl + v;
  }
}

__global__ __launch_bounds__(256) void scatter_kernel(const int* __restrict__ srcA,
                                                      const int* __restrict__ dstA,
                                                      int* __restrict__ cursor,
                                                      int* __restrict__ csr_src) {
  int i = blockIdx.x * 256 + threadIdx.x;
  if (i >= ET) return;
  int s, d;
  if (i < NE) { s = srcA[i]; d = dstA[i]; } else { s = d = i - NE; }
  int pos = atomicAdd(&cursor[d], 1);
  csr_src[pos] = s;
}

// ---- GEMM + fused att dots: H(f16) = A(N x 128) @ B(128 x NC) ----
// 64x64 tile, full-K LDS, grid=(ceil(N/64), NC/64). acc stays f32 in regs;
// a_s/a_d computed from exact f32 acc via shfl; H stored as f16 for gather.
template <int NC>
__global__ __launch_bounds__(256) void gemm_att_kernel(
    const float* __restrict__ A, const float* __restrict__ B,
    const float* __restrict__ atts, const float* __restrict__ attd,
    __half* __restrict__ Hh, float* __restrict__ a_s, float* __restrict__ a_d,
    int N) {
  constexpr int K = 128, BM = 64, BN = 64, KP = K + 4;
  __shared__ float Asl[BM][KP];
  __shared__ float Bsl[K][BN];
  const int tid = threadIdx.x;
  const int tx = tid & 15, ty = tid >> 4;
  const int row0 = blockIdx.x * BM;
  const int col0 = blockIdx.y * BN;
#pragma unroll
  for (int j = 0; j < 8; ++j) {
    int idx = j * 256 + tid;
    int r = idx >> 5, c4 = (idx & 31) << 2;
    int gr = row0 + r;
    float4 v = make_float4(0.f, 0.f, 0.f, 0.f);
    if (gr < N) v = *(const float4*)(A + (size_t)gr * K + c4);
    *(float4*)&Asl[r][c4] = v;
  }
#pragma unroll
  for (int j = 0; j < 8; ++j) {
    int idx = j * 256 + tid;
    int kr = idx >> 4, c4 = (idx & 15) << 2;
    *(float4*)&Bsl[kr][c4] = *(const float4*)(B + (size_t)kr * NC + col0 + c4);
  }
  __syncthreads();
  float acc[4][4];
#pragma unroll
  for (int i = 0; i < 4; ++i)
    acc[i][0] = acc[i][1] = acc[i][2] = acc[i][3] = 0.f;
#pragma unroll 2
  for (int k = 0; k < K; k += 4) {
    float4 b0 = *(const float4*)&Bsl[k + 0][tx * 4];
    float4 b1 = *(const float4*)&Bsl[k + 1][tx * 4];
    float4 b2 = *(const float4*)&Bsl[k + 2][tx * 4];
    float4 b3 = *(const float4*)&Bsl[k + 3][tx * 4];
#pragma unroll
    for (int i = 0; i < 4; ++i) {
      float4 a = *(const float4*)&Asl[ty * 4 + i][k];
      acc[i][0] += a.x * b0.x + a.y * b1.x + a.z * b2.x + a.w * b3.x;
      acc[i][1] += a.x * b0.y + a.y * b1.y + a.z * b2.y + a.w * b3.y;
      acc[i][2] += a.x * b0.z + a.y * b1.z + a.z * b2.z + a.w * b3.z;
      acc[i][3] += a.x * b0.w + a.y * b1.w + a.z * b2.w + a.w * b3.w;
    }
  }
  // attention weights for this thread's 4 global columns
  float asl[4], adl[4];
#pragma unroll
  for (int q = 0; q < 4; ++q) {
    asl[q] = atts[col0 + tx * 4 + q];
    adl[q] = attd[col0 + tx * 4 + q];
  }
#pragma unroll
  for (int i = 0; i < 4; ++i) {
    int gr = row0 + ty * 4 + i;
    float sp = acc[i][0] * asl[0] + acc[i][1] * asl[1] + acc[i][2] * asl[2] +
               acc[i][3] * asl[3];
    float dp = acc[i][0] * adl[0] + acc[i][1] * adl[1] + acc[i][2] * adl[2] +
               acc[i][3] * adl[3];
    if (NC == 128) {  // heads of 32 ch = 8-lane tx groups
      sp += __shfl_xor(sp, 1); sp += __shfl_xor(sp, 2); sp += __shfl_xor(sp, 4);
      dp += __shfl_xor(dp, 1); dp += __shfl_xor(dp, 2); dp += __shfl_xor(dp, 4);
      if ((tx & 7) == 0 && gr < N) {
        int hd = blockIdx.y * 2 + (tx >> 3);
        a_s[gr * 4 + hd] = sp;
        a_d[gr * 4 + hd] = dp;
      }
    } else {  // single 64-ch head = all 16 tx lanes
      sp += __shfl_xor(sp, 1); sp += __shfl_xor(sp, 2);
      sp += __shfl_xor(sp, 4); sp += __shfl_xor(sp, 8);
      dp += __shfl_xor(dp, 1); dp += __shfl_xor(dp, 2);
      dp += __shfl_xor(dp, 4); dp += __shfl_xor(dp, 8);
      if (tx == 0 && gr < N) {
        a_s[gr] = sp;
        a_d[gr] = dp;
      }
    }
    if (gr < N) {
      __half2 ha = __floats2half2_rn(acc[i][0], acc[i][1]);
      __half2 hb = __floats2half2_rn(acc[i][2], acc[i][3]);
      uint2 u;
      u.x = *(unsigned int*)&ha;
      u.y = *(unsigned int*)&hb;
      *(uint2*)(Hh + (size_t)gr * NC + col0 + tx * 4) = u;
    }
  }
}

__device__ inline float4 loadh4(const __half* p) {
  uint2 u = *(const uint2*)p;
  __half2 h01 = *(__half2*)&u.x;
  __half2 h23 = *(__half2*)&u.y;
  float2 f01 = __half22float2(h01);
  float2 f23 = __half22float2(h23);
  return make_float4(f01.x, f01.y, f23.x, f23.y);
}

// ---------------- layer-1 aggregation: wave/node, f16 gather ----------------
__global__ __launch_bounds__(256) void gat1_kernel(const int* __restrict__ rowptr,
                                                   const int* __restrict__ csr_src,
                                                   const __half* __restrict__ h1,
                                                   const float* __restrict__ as1,
                                                   const float* __restrict__ ad1,
                                                   const float* __restrict__ b1,
                                                   float* __restrict__ out1, int N) {
  int n = (blockIdx.x * 256 + threadIdx.x) >> 6;
  int l = threadIdx.x & 63;
  if (n >= N) return;
  int start = rowptr[n], end = rowptr[n + 1];
  int c = l & 31, half = l >> 5;
  int hB = c >> 3;
  float ad_b = ad1[n * 4 + hB];
  float ax = 0.f, ay = 0.f, az = 0.f, aw = 0.f, z = 0.f;
  int e = start + half;
  for (; e + 2 < end; e += 4) {
    int s0 = csr_src[e];
    int s1 = csr_src[e + 2];
    float a0 = as1[s0 * 4 + hB] + ad_b;
    float a1 = as1[s1 * 4 + hB] + ad_b;
    float4 g0 = loadh4(h1 + (size_t)s0 * 128 + 4 * c);
    float4 g1 = loadh4(h1 + (size_t)s1 * 128 + 4 * c);
    a0 = (a0 > 0.f) ? a0 : SLOPE * a0;
    a1 = (a1 > 0.f) ? a1 : SLOPE * a1;
    float w0 = __expf(a0), w1 = __expf(a1);
    ax += w0 * g0.x + w1 * g1.x;
    ay += w0 * g0.y + w1 * g1.y;
    az += w0 * g0.z + w1 * g1.z;
    aw += w0 * g0.w + w1 * g1.w;
    z += w0 + w1;
  }
  for (; e < end; e += 2) {
    int s = csr_src[e];
    float a = as1[s * 4 + hB] + ad_b;
    a = (a > 0.f) ? a : SLOPE * a;
    float w = __expf(a);
    float4 g = loadh4(h1 + (size_t)s * 128 + 4 * c);
    ax += w * g.x; ay += w * g.y; az += w * g.z; aw += w * g.w;
    z += w;
  }
  ax += __shfl_xor(ax, 32);
  ay += __shfl_xor(ay, 32);
  az += __shfl_xor(az, 32);
  aw += __shfl_xor(aw, 32);
  z += __shfl_xor(z, 32);
  if (half == 0) {
    float inv = 1.f / (z + GEPS);
    float4 bb = *(const float4*)(b1 + 4 * c);
    float4 o;
    o.x = fmaxf(ax * inv + bb.x, 0.f);
    o.y = fmaxf(ay * inv + bb.y, 0.f);
    o.z = fmaxf(az * inv + bb.z, 0.f);
    o.w = fmaxf(aw * inv + bb.w, 0.f);
    *(float4*)(out1 + (size_t)n * 128 + 4 * c) = o;
  }
}

// ---------------- layer-2 aggregation: wave/node, f16 gather ----------------
__global__ __launch_bounds__(256) void gat2_kernel(const int* __restrict__ rowptr,
                                                   const int* __restrict__ csr_src,
                                                   const __half* __restrict__ h2,
                                                   const float* __restrict__ as2,
                                                   const float* __restrict__ ad2,
                                                   const float* __restrict__ b2,
                                                   float* __restrict__ out, int N) {
  int n = (blockIdx.x * 256 + threadIdx.x) >> 6;
  int l = threadIdx.x & 63;
  if (n >= N) return;
  int start = rowptr[n], end = rowptr[n + 1];
  int c = l & 15, q = l >> 4;
  float ad = ad2[n];
  float ax = 0.f, ay = 0.f, az = 0.f, aw = 0.f, z = 0.f;
  int e = start + q;
  for (; e + 4 < end; e += 8) {
    int s0 = csr_src[e];
    int s1 = csr_src[e + 4];
    float a0 = as2[s0] + ad;
    float a1 = as2[s1] + ad;
    float4 g0 = loadh4(h2 + (size_t)s0 * 64 + 4 * c);
    float4 g1 = loadh4(h2 + (size_t)s1 * 64 + 4 * c);
    a0 = (a0 > 0.f) ? a0 : SLOPE * a0;
    a1 = (a1 > 0.f) ? a1 : SLOPE * a1;
    float w0 = __expf(a0), w1 = __expf(a1);
    ax += w0 * g0.x + w1 * g1.x;
    ay += w0 * g0.y + w1 * g1.y;
    az += w0 * g0.z + w1 * g1.z;
    aw += w0 * g0.w + w1 * g1.w;
    z += w0 + w1;
  }
  for (; e < end; e += 4) {
    int s = csr_src[e];
    float a = as2[s] + ad;
    a = (a > 0.f) ? a : SLOPE * a;
    float w = __expf(a);
    float4 g = loadh4(h2 + (size_t)s * 64 + 4 * c);
    ax += w * g.x; ay += w * g.y; az += w * g.z; aw += w * g.w;
    z += w;
  }
  ax += __shfl_xor(ax, 16); ax += __shfl_xor(ax, 32);
  ay += __shfl_xor(ay, 16); ay += __shfl_xor(ay, 32);
  az += __shfl_xor(az, 16); az += __shfl_xor(az, 32);
  aw += __shfl_xor(aw, 16); aw += __shfl_xor(aw, 32);
  z += __shfl_xor(z, 16);  z += __shfl_xor(z, 32);
  if (q == 0) {
    float inv = 1.f / (z + GEPS);
    float4 bb = *(const float4*)(b2 + 4 * c);
    float4 o;
    o.x = fmaxf(ax * inv + bb.x, 0.f);
    o.y = fmaxf(ay * inv + bb.y, 0.f);
    o.z = fmaxf(az * inv + bb.z, 0.f);
    o.w = fmaxf(aw * inv + bb.w, 0.f);
    *(float4*)(out + (size_t)n * 64 + 4 * c) = o;
  }
}

extern "C" void kernel_launch(void* const* d_in, const int* in_sizes, int n_in,
                              void* d_out, int out_size, void* d_ws, size_t ws_size,
                              hipStream_t stream) {
  const float* x = (const float*)d_in[0];
  const int* ei = (const int*)d_in[1];
  const float* W1 = (const float*)d_in[2];
  const float* att_s1 = (const float*)d_in[3];
  const float* att_d1 = (const float*)d_in[4];
  const float* b1 = (const float*)d_in[5];
  const float* W2 = (const float*)d_in[6];
  const float* att_s2 = (const float*)d_in[7];
  const float* att_d2 = (const float*)d_in[8];
  const float* b2 = (const float*)d_in[9];
  float* out = (float*)d_out;

  char* ws = (char*)d_ws;
  size_t off = 0;
  auto alloc = [&](size_t bytes) {
    off = (off + 255) & ~(size_t)255;
    void* p = ws + off;
    off += bytes;
    return p;
  };
  int* deg = (int*)alloc((NN + 1) * sizeof(int));
  int* rowptr = (int*)alloc((NN + 1) * sizeof(int));
  int* cursor = (int*)alloc((size_t)NN * sizeof(int));
  int* bsum = (int*)alloc(NB * sizeof(int));
  int* boff = (int*)alloc(NB * sizeof(int));
  int* csr_src = (int*)alloc((size_t)ET * sizeof(int));
  __half* h1 = (__half*)alloc((size_t)NN * 128 * sizeof(__half));
  float* as1 = (float*)alloc((size_t)NN * 4 * sizeof(float));
  float* ad1 = (float*)alloc((size_t)NN * 4 * sizeof(float));
  float* out1 = (float*)alloc((size_t)NN * 128 * sizeof(float));
  __half* hh2 = h1;  // layer-2 f16 features reuse h1 (dead after gat1)
  float* as2 = as1;
  float* ad2 = ad1;

  const int* src = ei;
  const int* dst = ei + NE;

  hipMemsetAsync(deg, 0, (NN + 1) * sizeof(int), stream);
  int ebks = (ET + 255) / 256;
  hipLaunchKernelGGL(hist_kernel, dim3(ebks), dim3(256), 0, stream, dst, deg);
  hipLaunchKernelGGL(part_kernel, dim3(NB), dim3(256), 0, stream, deg, bsum);
  hipLaunchKernelGGL(bscan_kernel, dim3(1), dim3(256), 0, stream, bsum, boff);
  hipLaunchKernelGGL(rowptr_kernel, dim3(NB), dim3(256), 0, stream, deg, boff, rowptr,
                     cursor);
  hipLaunchKernelGGL(scatter_kernel, dim3(ebks), dim3(256), 0, stream, src, dst, cursor,
                     csr_src);

  int rbks = (NN + 63) / 64;
  hipLaunchKernelGGL((gemm_att_kernel<128>), dim3(rbks, 2), dim3(256), 0, stream, x, W1,
                     att_s1, att_d1, h1, as1, ad1, NN);
  hipLaunchKernelGGL(gat1_kernel, dim3((NN + 3) / 4), dim3(256), 0, stream, rowptr,
                     csr_src, h1, as1, ad1, b1, out1, NN);

  hipLaunchKernelGGL((gemm_att_kernel<64>), dim3(rbks, 1), dim3(256), 0, stream, out1,
                     W2, att_s2, att_d2, hh2, as2, ad2, NN);
  hipLaunchKernelGGL(gat2_kernel, dim3((NN + 3) / 4), dim3(256), 0, stream, rowptr,
                     csr_src, hh2, as2, ad2, b2, out, NN);
}

// Round 6
// 237.355 us; speedup vs baseline: 2.5597x; 1.0183x over previous
//
#include <hip/hip_runtime.h>
#include <hip/hip_fp16.h>

#define NN 50000
#define NE 800000
#define ET (NE + NN)
#define SLOPE 0.2f
#define GEPS 1e-16f
#define NB 196   // (NN+255)/256
#define NQ (NE / 4)  // 200000 edges per strided batch

// ---------------- CSR build ----------------
// 4 edges/thread, strided batches keep each load coalesced; 4 independent
// atomic chains per thread for memory-level parallelism.
__global__ __launch_bounds__(256) void hist_kernel(const int* __restrict__ dst,
                                                   int* __restrict__ deg) {
  int tid = blockIdx.x * 256 + threadIdx.x;
  if (tid >= NQ) return;
  int d0 = dst[tid];
  int d1 = dst[tid + NQ];
  int d2 = dst[tid + 2 * NQ];
  int d3 = dst[tid + 3 * NQ];
  atomicAdd(&deg[d0], 1);
  atomicAdd(&deg[d1], 1);
  atomicAdd(&deg[d2], 1);
  atomicAdd(&deg[d3], 1);
}

// deg counts only real edges; the +1 self-loop is folded into the scans.
__global__ __launch_bounds__(256) void part_kernel(const int* __restrict__ deg,
                                                   int* __restrict__ bsum) {
  __shared__ int lds[256];
  int t = threadIdx.x;
  int i = blockIdx.x * 256 + t;
  lds[t] = (i < NN) ? (deg[i] + 1) : 0;
  __syncthreads();
  for (int off = 128; off > 0; off >>= 1) {
    if (t < off) lds[t] += lds[t + off];
    __syncthreads();
  }
  if (t == 0) bsum[blockIdx.x] = lds[0];
}

__global__ __launch_bounds__(256) void bscan_kernel(const int* __restrict__ bsum,
                                                    int* __restrict__ boff) {
  __shared__ int lds[256];
  int t = threadIdx.x;
  int v = (t < NB) ? bsum[t] : 0;
  lds[t] = v;
  __syncthreads();
  for (int off = 1; off < 256; off <<= 1) {
    int u = (t >= off) ? lds[t - off] : 0;
    __syncthreads();
    lds[t] += u;
    __syncthreads();
  }
  if (t < NB) boff[t] = lds[t] - v;
}

// rowptr + cursor + self-loop emission (csr[rowptr[i]] = i, cursor starts +1)
__global__ __launch_bounds__(256) void rowptr_kernel(const int* __restrict__ deg,
                                                     const int* __restrict__ boff,
                                                     int* __restrict__ rowptr,
                                                     int* __restrict__ cursor,
                                                     unsigned short* __restrict__ csr) {
  __shared__ int lds[256];
  int t = threadIdx.x;
  int i = blockIdx.x * 256 + t;
  int v = (i < NN) ? (deg[i] + 1) : 0;
  lds[t] = v;
  __syncthreads();
  for (int off = 1; off < 256; off <<= 1) {
    int u = (t >= off) ? lds[t - off] : 0;
    __syncthreads();
    lds[t] += u;
    __syncthreads();
  }
  if (i < NN) {
    int excl = boff[blockIdx.x] + lds[t] - v;
    rowptr[i] = excl;
    cursor[i] = excl + 1;          // slot 0 = self-loop
    csr[excl] = (unsigned short)i; // emit self-loop (monotone writes)
    if (i == NN - 1) rowptr[NN] = excl + v;
  }
}

__global__ __launch_bounds__(256) void scatter_kernel(
    const int* __restrict__ srcA, const int* __restrict__ dstA,
    int* __restrict__ cursor, unsigned short* __restrict__ csr) {
  int tid = blockIdx.x * 256 + threadIdx.x;
  if (tid >= NQ) return;
  int s0 = srcA[tid];
  int s1 = srcA[tid + NQ];
  int s2 = srcA[tid + 2 * NQ];
  int s3 = srcA[tid + 3 * NQ];
  int d0 = dstA[tid];
  int d1 = dstA[tid + NQ];
  int d2 = dstA[tid + 2 * NQ];
  int d3 = dstA[tid + 3 * NQ];
  int p0 = atomicAdd(&cursor[d0], 1);
  int p1 = atomicAdd(&cursor[d1], 1);
  int p2 = atomicAdd(&cursor[d2], 1);
  int p3 = atomicAdd(&cursor[d3], 1);
  csr[p0] = (unsigned short)s0;
  csr[p1] = (unsigned short)s1;
  csr[p2] = (unsigned short)s2;
  csr[p3] = (unsigned short)s3;
}

// ---- GEMM + fused att dots: H(f16) = A(N x 128) @ B(128 x NC) ----
template <int NC>
__global__ __launch_bounds__(256) void gemm_att_kernel(
    const float* __restrict__ A, const float* __restrict__ B,
    const float* __restrict__ atts, const float* __restrict__ attd,
    __half* __restrict__ Hh, float* __restrict__ a_s, float* __restrict__ a_d,
    int N) {
  constexpr int K = 128, BM = 64, BN = 64, KP = K + 4;
  __shared__ float Asl[BM][KP];
  __shared__ float Bsl[K][BN];
  const int tid = threadIdx.x;
  const int tx = tid & 15, ty = tid >> 4;
  const int row0 = blockIdx.x * BM;
  const int col0 = blockIdx.y * BN;
#pragma unroll
  for (int j = 0; j < 8; ++j) {
    int idx = j * 256 + tid;
    int r = idx >> 5, c4 = (idx & 31) << 2;
    int gr = row0 + r;
    float4 v = make_float4(0.f, 0.f, 0.f, 0.f);
    if (gr < N) v = *(const float4*)(A + (size_t)gr * K + c4);
    *(float4*)&Asl[r][c4] = v;
  }
#pragma unroll
  for (int j = 0; j < 8; ++j) {
    int idx = j * 256 + tid;
    int kr = idx >> 4, c4 = (idx & 15) << 2;
    *(float4*)&Bsl[kr][c4] = *(const float4*)(B + (size_t)kr * NC + col0 + c4);
  }
  __syncthreads();
  float acc[4][4];
#pragma unroll
  for (int i = 0; i < 4; ++i)
    acc[i][0] = acc[i][1] = acc[i][2] = acc[i][3] = 0.f;
#pragma unroll 2
  for (int k = 0; k < K; k += 4) {
    float4 b0 = *(const float4*)&Bsl[k + 0][tx * 4];
    float4 b1 = *(const float4*)&Bsl[k + 1][tx * 4];
    float4 b2 = *(const float4*)&Bsl[k + 2][tx * 4];
    float4 b3 = *(const float4*)&Bsl[k + 3][tx * 4];
#pragma unroll
    for (int i = 0; i < 4; ++i) {
      float4 a = *(const float4*)&Asl[ty * 4 + i][k];
      acc[i][0] += a.x * b0.x + a.y * b1.x + a.z * b2.x + a.w * b3.x;
      acc[i][1] += a.x * b0.y + a.y * b1.y + a.z * b2.y + a.w * b3.y;
      acc[i][2] += a.x * b0.z + a.y * b1.z + a.z * b2.z + a.w * b3.z;
      acc[i][3] += a.x * b0.w + a.y * b1.w + a.z * b2.w + a.w * b3.w;
    }
  }
  float asl[4], adl[4];
#pragma unroll
  for (int q = 0; q < 4; ++q) {
    asl[q] = atts[col0 + tx * 4 + q];
    adl[q] = attd[col0 + tx * 4 + q];
  }
#pragma unroll
  for (int i = 0; i < 4; ++i) {
    int gr = row0 + ty * 4 + i;
    float sp = acc[i][0] * asl[0] + acc[i][1] * asl[1] + acc[i][2] * asl[2] +
               acc[i][3] * asl[3];
    float dp = acc[i][0] * adl[0] + acc[i][1] * adl[1] + acc[i][2] * adl[2] +
               acc[i][3] * adl[3];
    if (NC == 128) {
      sp += __shfl_xor(sp, 1); sp += __shfl_xor(sp, 2); sp += __shfl_xor(sp, 4);
      dp += __shfl_xor(dp, 1); dp += __shfl_xor(dp, 2); dp += __shfl_xor(dp, 4);
      if ((tx & 7) == 0 && gr < N) {
        int hd = blockIdx.y * 2 + (tx >> 3);
        a_s[gr * 4 + hd] = sp;
        a_d[gr * 4 + hd] = dp;
      }
    } else {
      sp += __shfl_xor(sp, 1); sp += __shfl_xor(sp, 2);
      sp += __shfl_xor(sp, 4); sp += __shfl_xor(sp, 8);
      dp += __shfl_xor(dp, 1); dp += __shfl_xor(dp, 2);
      dp += __shfl_xor(dp, 4); dp += __shfl_xor(dp, 8);
      if (tx == 0 && gr < N) {
        a_s[gr] = sp;
        a_d[gr] = dp;
      }
    }
    if (gr < N) {
      __half2 ha = __floats2half2_rn(acc[i][0], acc[i][1]);
      __half2 hb = __floats2half2_rn(acc[i][2], acc[i][3]);
      uint2 u;
      u.x = *(unsigned int*)&ha;
      u.y = *(unsigned int*)&hb;
      *(uint2*)(Hh + (size_t)gr * NC + col0 + tx * 4) = u;
    }
  }
}

__device__ inline float4 loadh4(const __half* p) {
  uint2 u = *(const uint2*)p;
  __half2 h01 = *(__half2*)&u.x;
  __half2 h23 = *(__half2*)&u.y;
  float2 f01 = __half22float2(h01);
  float2 f23 = __half22float2(h23);
  return make_float4(f01.x, f01.y, f23.x, f23.y);
}

// ---------------- layer-1 aggregation ----------------
__global__ __launch_bounds__(256) void gat1_kernel(
    const int* __restrict__ rowptr, const unsigned short* __restrict__ csr_src,
    const __half* __restrict__ h1, const float* __restrict__ as1,
    const float* __restrict__ ad1, const float* __restrict__ b1,
    float* __restrict__ out1, int N) {
  int n = (blockIdx.x * 256 + threadIdx.x) >> 6;
  int l = threadIdx.x & 63;
  if (n >= N) return;
  int start = rowptr[n], end = rowptr[n + 1];
  int c = l & 31, half = l >> 5;
  int hB = c >> 3;
  float ad_b = ad1[n * 4 + hB];
  float ax = 0.f, ay = 0.f, az = 0.f, aw = 0.f, z = 0.f;
  int e = start + half;
  for (; e + 2 < end; e += 4) {
    int s0 = csr_src[e];
    int s1 = csr_src[e + 2];
    float a0 = as1[s0 * 4 + hB] + ad_b;
    float a1 = as1[s1 * 4 + hB] + ad_b;
    float4 g0 = loadh4(h1 + (size_t)s0 * 128 + 4 * c);
    float4 g1 = loadh4(h1 + (size_t)s1 * 128 + 4 * c);
    a0 = (a0 > 0.f) ? a0 : SLOPE * a0;
    a1 = (a1 > 0.f) ? a1 : SLOPE * a1;
    float w0 = __expf(a0), w1 = __expf(a1);
    ax += w0 * g0.x + w1 * g1.x;
    ay += w0 * g0.y + w1 * g1.y;
    az += w0 * g0.z + w1 * g1.z;
    aw += w0 * g0.w + w1 * g1.w;
    z += w0 + w1;
  }
  for (; e < end; e += 2) {
    int s = csr_src[e];
    float a = as1[s * 4 + hB] + ad_b;
    a = (a > 0.f) ? a : SLOPE * a;
    float w = __expf(a);
    float4 g = loadh4(h1 + (size_t)s * 128 + 4 * c);
    ax += w * g.x; ay += w * g.y; az += w * g.z; aw += w * g.w;
    z += w;
  }
  ax += __shfl_xor(ax, 32);
  ay += __shfl_xor(ay, 32);
  az += __shfl_xor(az, 32);
  aw += __shfl_xor(aw, 32);
  z += __shfl_xor(z, 32);
  if (half == 0) {
    float inv = 1.f / (z + GEPS);
    float4 bb = *(const float4*)(b1 + 4 * c);
    float4 o;
    o.x = fmaxf(ax * inv + bb.x, 0.f);
    o.y = fmaxf(ay * inv + bb.y, 0.f);
    o.z = fmaxf(az * inv + bb.z, 0.f);
    o.w = fmaxf(aw * inv + bb.w, 0.f);
    *(float4*)(out1 + (size_t)n * 128 + 4 * c) = o;
  }
}

// ---------------- layer-2 aggregation ----------------
__global__ __launch_bounds__(256) void gat2_kernel(
    const int* __restrict__ rowptr, const unsigned short* __restrict__ csr_src,
    const __half* __restrict__ h2, const float* __restrict__ as2,
    const float* __restrict__ ad2, const float* __restrict__ b2,
    float* __restrict__ out, int N) {
  int n = (blockIdx.x * 256 + threadIdx.x) >> 6;
  int l = threadIdx.x & 63;
  if (n >= N) return;
  int start = rowptr[n], end = rowptr[n + 1];
  int c = l & 15, q = l >> 4;
  float ad = ad2[n];
  float ax = 0.f, ay = 0.f, az = 0.f, aw = 0.f, z = 0.f;
  int e = start + q;
  for (; e + 4 < end; e += 8) {
    int s0 = csr_src[e];
    int s1 = csr_src[e + 4];
    float a0 = as2[s0] + ad;
    float a1 = as2[s1] + ad;
    float4 g0 = loadh4(h2 + (size_t)s0 * 64 + 4 * c);
    float4 g1 = loadh4(h2 + (size_t)s1 * 64 + 4 * c);
    a0 = (a0 > 0.f) ? a0 : SLOPE * a0;
    a1 = (a1 > 0.f) ? a1 : SLOPE * a1;
    float w0 = __expf(a0), w1 = __expf(a1);
    ax += w0 * g0.x + w1 * g1.x;
    ay += w0 * g0.y + w1 * g1.y;
    az += w0 * g0.z + w1 * g1.z;
    aw += w0 * g0.w + w1 * g1.w;
    z += w0 + w1;
  }
  for (; e < end; e += 4) {
    int s = csr_src[e];
    float a = as2[s] + ad;
    a = (a > 0.f) ? a : SLOPE * a;
    float w = __expf(a);
    float4 g = loadh4(h2 + (size_t)s * 64 + 4 * c);
    ax += w * g.x; ay += w * g.y; az += w * g.z; aw += w * g.w;
    z += w;
  }
  ax += __shfl_xor(ax, 16); ax += __shfl_xor(ax, 32);
  ay += __shfl_xor(ay, 16); ay += __shfl_xor(ay, 32);
  az += __shfl_xor(az, 16); az += __shfl_xor(az, 32);
  aw += __shfl_xor(aw, 16); aw += __shfl_xor(aw, 32);
  z += __shfl_xor(z, 16);  z += __shfl_xor(z, 32);
  if (q == 0) {
    float inv = 1.f / (z + GEPS);
    float4 bb = *(const float4*)(b2 + 4 * c);
    float4 o;
    o.x = fmaxf(ax * inv + bb.x, 0.f);
    o.y = fmaxf(ay * inv + bb.y, 0.f);
    o.z = fmaxf(az * inv + bb.z, 0.f);
    o.w = fmaxf(aw * inv + bb.w, 0.f);
    *(float4*)(out + (size_t)n * 64 + 4 * c) = o;
  }
}

extern "C" void kernel_launch(void* const* d_in, const int* in_sizes, int n_in,
                              void* d_out, int out_size, void* d_ws, size_t ws_size,
                              hipStream_t stream) {
  const float* x = (const float*)d_in[0];
  const int* ei = (const int*)d_in[1];
  const float* W1 = (const float*)d_in[2];
  const float* att_s1 = (const float*)d_in[3];
  const float* att_d1 = (const float*)d_in[4];
  const float* b1 = (const float*)d_in[5];
  const float* W2 = (const float*)d_in[6];
  const float* att_s2 = (const float*)d_in[7];
  const float* att_d2 = (const float*)d_in[8];
  const float* b2 = (const float*)d_in[9];
  float* out = (float*)d_out;

  char* ws = (char*)d_ws;
  size_t off = 0;
  auto alloc = [&](size_t bytes) {
    off = (off + 255) & ~(size_t)255;
    void* p = ws + off;
    off += bytes;
    return p;
  };
  int* deg = (int*)alloc((NN + 1) * sizeof(int));
  int* rowptr = (int*)alloc((NN + 1) * sizeof(int));
  int* cursor = (int*)alloc((size_t)NN * sizeof(int));
  int* bsum = (int*)alloc(NB * sizeof(int));
  int* boff = (int*)alloc(NB * sizeof(int));
  unsigned short* csr_src = (unsigned short*)alloc((size_t)ET * sizeof(unsigned short));
  __half* h1 = (__half*)alloc((size_t)NN * 128 * sizeof(__half));
  float* as1 = (float*)alloc((size_t)NN * 4 * sizeof(float));
  float* ad1 = (float*)alloc((size_t)NN * 4 * sizeof(float));
  float* out1 = (float*)alloc((size_t)NN * 128 * sizeof(float));
  __half* hh2 = h1;
  float* as2 = as1;
  float* ad2 = ad1;

  const int* src = ei;
  const int* dst = ei + NE;

  hipMemsetAsync(deg, 0, (NN + 1) * sizeof(int), stream);
  int qbks = (NQ + 255) / 256;
  hipLaunchKernelGGL(hist_kernel, dim3(qbks), dim3(256), 0, stream, dst, deg);
  hipLaunchKernelGGL(part_kernel, dim3(NB), dim3(256), 0, stream, deg, bsum);
  hipLaunchKernelGGL(bscan_kernel, dim3(1), dim3(256), 0, stream, bsum, boff);
  hipLaunchKernelGGL(rowptr_kernel, dim3(NB), dim3(256), 0, stream, deg, boff, rowptr,
                     cursor, csr_src);
  hipLaunchKernelGGL(scatter_kernel, dim3(qbks), dim3(256), 0, stream, src, dst, cursor,
                     csr_src);

  int rbks = (NN + 63) / 64;
  hipLaunchKernelGGL((gemm_att_kernel<128>), dim3(rbks, 2), dim3(256), 0, stream, x, W1,
                     att_s1, att_d1, h1, as1, ad1, NN);
  hipLaunchKernelGGL(gat1_kernel, dim3((NN + 3) / 4), dim3(256), 0, stream, rowptr,
                     csr_src, h1, as1, ad1, b1, out1, NN);

  hipLaunchKernelGGL((gemm_att_kernel<64>), dim3(rbks, 1), dim3(256), 0, stream, out1,
                     W2, att_s2, att_d2, hh2, as2, ad2, NN);
  hipLaunchKernelGGL(gat2_kernel, dim3((NN + 3) / 4), dim3(256), 0, stream, rowptr,
                     csr_src, hh2, as2, ad2, b2, out, NN);
}

// Round 7
// 202.401 us; speedup vs baseline: 3.0017x; 1.1727x over previous
//
#include <hip/hip_runtime.h>

#define NN 50000
#define NE 800000
#define ET (NE + NN)
#define SLOPE 0.2f
#define GEPS 1e-16f
#define NB 196       // (NN+255)/256
#define NQ (NE / 4)  // edges per strided batch

typedef _Float16 f16;
typedef f16 f16x4 __attribute__((ext_vector_type(4)));
typedef f16 f16x8 __attribute__((ext_vector_type(8)));
typedef float f32x4 __attribute__((ext_vector_type(4)));

// ---------------- CSR build ----------------
__global__ __launch_bounds__(256) void hist_kernel(const int* __restrict__ dst,
                                                   int* __restrict__ deg) {
  int tid = blockIdx.x * 256 + threadIdx.x;
  if (tid >= NQ) return;
  int d0 = dst[tid];
  int d1 = dst[tid + NQ];
  int d2 = dst[tid + 2 * NQ];
  int d3 = dst[tid + 3 * NQ];
  atomicAdd(&deg[d0], 1);
  atomicAdd(&deg[d1], 1);
  atomicAdd(&deg[d2], 1);
  atomicAdd(&deg[d3], 1);
}

__global__ __launch_bounds__(256) void part_kernel(const int* __restrict__ deg,
                                                   int* __restrict__ bsum) {
  __shared__ int lds[256];
  int t = threadIdx.x;
  int i = blockIdx.x * 256 + t;
  lds[t] = (i < NN) ? (deg[i] + 1) : 0;
  __syncthreads();
  for (int off = 128; off > 0; off >>= 1) {
    if (t < off) lds[t] += lds[t + off];
    __syncthreads();
  }
  if (t == 0) bsum[blockIdx.x] = lds[0];
}

__global__ __launch_bounds__(256) void bscan_kernel(const int* __restrict__ bsum,
                                                    int* __restrict__ boff) {
  __shared__ int lds[256];
  int t = threadIdx.x;
  int v = (t < NB) ? bsum[t] : 0;
  lds[t] = v;
  __syncthreads();
  for (int off = 1; off < 256; off <<= 1) {
    int u = (t >= off) ? lds[t - off] : 0;
    __syncthreads();
    lds[t] += u;
    __syncthreads();
  }
  if (t < NB) boff[t] = lds[t] - v;
}

__global__ __launch_bounds__(256) void rowptr_kernel(const int* __restrict__ deg,
                                                     const int* __restrict__ boff,
                                                     int* __restrict__ rowptr,
                                                     int* __restrict__ cursor,
                                                     unsigned short* __restrict__ csr) {
  __shared__ int lds[256];
  int t = threadIdx.x;
  int i = blockIdx.x * 256 + t;
  int v = (i < NN) ? (deg[i] + 1) : 0;
  lds[t] = v;
  __syncthreads();
  for (int off = 1; off < 256; off <<= 1) {
    int u = (t >= off) ? lds[t - off] : 0;
    __syncthreads();
    lds[t] += u;
    __syncthreads();
  }
  if (i < NN) {
    int excl = boff[blockIdx.x] + lds[t] - v;
    rowptr[i] = excl;
    cursor[i] = excl + 1;
    csr[excl] = (unsigned short)i;  // self-loop in slot 0
    if (i == NN - 1) rowptr[NN] = excl + v;
  }
}

__global__ __launch_bounds__(256) void scatter_kernel(
    const int* __restrict__ srcA, const int* __restrict__ dstA,
    int* __restrict__ cursor, unsigned short* __restrict__ csr) {
  int tid = blockIdx.x * 256 + threadIdx.x;
  if (tid >= NQ) return;
  int s0 = srcA[tid];
  int s1 = srcA[tid + NQ];
  int s2 = srcA[tid + 2 * NQ];
  int s3 = srcA[tid + 3 * NQ];
  int d0 = dstA[tid];
  int d1 = dstA[tid + NQ];
  int d2 = dstA[tid + 2 * NQ];
  int d3 = dstA[tid + 3 * NQ];
  int p0 = atomicAdd(&cursor[d0], 1);
  int p1 = atomicAdd(&cursor[d1], 1);
  int p2 = atomicAdd(&cursor[d2], 1);
  int p3 = atomicAdd(&cursor[d3], 1);
  csr[p0] = (unsigned short)s0;
  csr[p1] = (unsigned short)s1;
  csr[p2] = (unsigned short)s2;
  csr[p3] = (unsigned short)s3;
}

// ---- W prep: split f32 W[K][NC] into hi/lo f16, transposed to [NC][K] ----
// wt layout (f16 elems): [0]=W1hi(128x128) [16384]=W1lo [32768]=W2hi(64x128)
// [40960]=W2lo
__global__ __launch_bounds__(256) void wprep_kernel(const float* __restrict__ W1,
                                                    const float* __restrict__ W2,
                                                    f16* __restrict__ wt) {
  int idx = blockIdx.x * 256 + threadIdx.x;
  if (idx < 16384) {
    int c = idx >> 7, k = idx & 127;
    float w = W1[k * 128 + c];
    f16 hi = (f16)w;
    f16 lo = (f16)(w - (float)hi);
    wt[c * 128 + k] = hi;
    wt[16384 + c * 128 + k] = lo;
  } else if (idx < 24576) {
    int i2 = idx - 16384;
    int c = i2 >> 7, k = i2 & 127;
    float w = W2[k * 64 + c];
    f16 hi = (f16)w;
    f16 lo = (f16)(w - (float)hi);
    wt[32768 + c * 128 + k] = hi;
    wt[40960 + c * 128 + k] = lo;
  }
}

// ---- MFMA GEMM + fused att dots: H(f16) = A(N x 128) @ W(128 x NC) ----
// 64x64 block, full-K LDS, W as hi+lo f16 (error ~exact W), f32 accum.
// grid = (ceil(N/64), NC/64).
template <int NC, bool AF32>
__global__ __launch_bounds__(256) void mfma_gemm_kernel(
    const void* __restrict__ Av, const f16* __restrict__ whi,
    const f16* __restrict__ wlo, const float* __restrict__ atts,
    const float* __restrict__ attd, f16* __restrict__ Hh,
    float* __restrict__ a_s, float* __restrict__ a_d, int N) {
  constexpr int K = 128, BM = 64, KP = K + 8;  // 272B rows: bank-safe
  __shared__ f16 Ah[BM * KP];
  __shared__ f16 Wh[64 * KP];
  __shared__ f16 Wl[64 * KP];
  const int tid = threadIdx.x;
  const int row0 = blockIdx.x * BM;
  const int col0 = blockIdx.y * 64;
  if (AF32) {
    const float* A = (const float*)Av;
#pragma unroll
    for (int j = 0; j < 8; ++j) {
      int idx = j * 256 + tid;
      int r = idx >> 5, col = (idx & 31) << 2;
      int gr = row0 + r;
      float4 v = make_float4(0.f, 0.f, 0.f, 0.f);
      if (gr < N) v = *(const float4*)(A + (size_t)gr * K + col);
      f16x4 hv = {(f16)v.x, (f16)v.y, (f16)v.z, (f16)v.w};
      *(f16x4*)&Ah[r * KP + col] = hv;
    }
  } else {
    const f16* A = (const f16*)Av;
#pragma unroll
    for (int j = 0; j < 4; ++j) {
      int idx = j * 256 + tid;
      int r = idx >> 4, col = (idx & 15) << 3;
      int gr = row0 + r;
      f16x8 v = {};
      if (gr < N) v = *(const f16x8*)(A + (size_t)gr * K + col);
      *(f16x8*)&Ah[r * KP + col] = v;
    }
  }
#pragma unroll
  for (int j = 0; j < 4; ++j) {
    int idx = j * 256 + tid;
    int r = idx >> 4, col = (idx & 15) << 3;
    *(f16x8*)&Wh[r * KP + col] =
        *(const f16x8*)(whi + (size_t)(col0 + r) * K + col);
    *(f16x8*)&Wl[r * KP + col] =
        *(const f16x8*)(wlo + (size_t)(col0 + r) * K + col);
  }
  __syncthreads();
  const int lane = tid & 63;
  const int w = tid >> 6;
  const int lr = lane & 15;
  const int lk = (lane >> 4) << 3;
  f32x4 acc[4];
#pragma unroll
  for (int cf = 0; cf < 4; ++cf) acc[cf] = (f32x4){0.f, 0.f, 0.f, 0.f};
  const f16* arow = Ah + (w * 16 + lr) * KP + lk;
  const f16* bhrow = Wh + lr * KP + lk;
  const f16* blrow = Wl + lr * KP + lk;
#pragma unroll
  for (int ks = 0; ks < 4; ++ks) {
    int k0 = ks * 32;
    f16x8 af = *(const f16x8*)(arow + k0);
#pragma unroll
    for (int cf = 0; cf < 4; ++cf) {
      f16x8 bh = *(const f16x8*)(bhrow + cf * 16 * KP + k0);
      f16x8 bl = *(const f16x8*)(blrow + cf * 16 * KP + k0);
      acc[cf] = __builtin_amdgcn_mfma_f32_16x16x32_f16(af, bh, acc[cf], 0, 0, 0);
      acc[cf] = __builtin_amdgcn_mfma_f32_16x16x32_f16(af, bl, acc[cf], 0, 0, 0);
    }
  }
  // C/D frag: col = lane&15 (lr), row = (lane>>4)*4 + reg  [m89-verified]
  const int rbase = row0 + w * 16 + ((lane >> 4) << 2);
#pragma unroll
  for (int cf = 0; cf < 4; ++cf) {
    int col = col0 + cf * 16 + lr;
#pragma unroll
    for (int r4 = 0; r4 < 4; ++r4) {
      int gr = rbase + r4;
      if (gr < N) Hh[(size_t)gr * NC + col] = (f16)acc[cf][r4];
    }
  }
  float asc[4], adc[4];
#pragma unroll
  for (int cf = 0; cf < 4; ++cf) {
    asc[cf] = atts[col0 + cf * 16 + lr];
    adc[cf] = attd[col0 + cf * 16 + lr];
  }
  if (NC == 128) {
#pragma unroll
    for (int m = 0; m < 2; ++m) {
#pragma unroll
      for (int r4 = 0; r4 < 4; ++r4) {
        float sp = acc[2 * m][r4] * asc[2 * m] + acc[2 * m + 1][r4] * asc[2 * m + 1];
        float dp = acc[2 * m][r4] * adc[2 * m] + acc[2 * m + 1][r4] * adc[2 * m + 1];
        sp += __shfl_xor(sp, 1); sp += __shfl_xor(sp, 2);
        sp += __shfl_xor(sp, 4); sp += __shfl_xor(sp, 8);
        dp += __shfl_xor(dp, 1); dp += __shfl_xor(dp, 2);
        dp += __shfl_xor(dp, 4); dp += __shfl_xor(dp, 8);
        int gr = rbase + r4;
        if (lr == 0 && gr < N) {
          int hd = blockIdx.y * 2 + m;
          a_s[gr * 4 + hd] = sp;
          a_d[gr * 4 + hd] = dp;
        }
      }
    }
  } else {
#pragma unroll
    for (int r4 = 0; r4 < 4; ++r4) {
      float sp = acc[0][r4] * asc[0] + acc[1][r4] * asc[1] +
                 acc[2][r4] * asc[2] + acc[3][r4] * asc[3];
      float dp = acc[0][r4] * adc[0] + acc[1][r4] * adc[1] +
                 acc[2][r4] * adc[2] + acc[3][r4] * adc[3];
      sp += __shfl_xor(sp, 1); sp += __shfl_xor(sp, 2);
      sp += __shfl_xor(sp, 4); sp += __shfl_xor(sp, 8);
      dp += __shfl_xor(dp, 1); dp += __shfl_xor(dp, 2);
      dp += __shfl_xor(dp, 4); dp += __shfl_xor(dp, 8);
      int gr = rbase + r4;
      if (lr == 0 && gr < N) {
        a_s[gr] = sp;
        a_d[gr] = dp;
      }
    }
  }
}

__device__ inline float4 loadh4(const f16* p) {
  f16x4 h = *(const f16x4*)p;
  return make_float4((float)h[0], (float)h[1], (float)h[2], (float)h[3]);
}

// ---------------- layer-1 aggregation (out f16 for gemm2) ----------------
__global__ __launch_bounds__(256) void gat1_kernel(
    const int* __restrict__ rowptr, const unsigned short* __restrict__ csr_src,
    const f16* __restrict__ h1, const float* __restrict__ as1,
    const float* __restrict__ ad1, const float* __restrict__ b1,
    f16* __restrict__ out1, int N) {
  int n = (blockIdx.x * 256 + threadIdx.x) >> 6;
  int l = threadIdx.x & 63;
  if (n >= N) return;
  int start = rowptr[n], end = rowptr[n + 1];
  int c = l & 31, half = l >> 5;
  int hB = c >> 3;
  float ad_b = ad1[n * 4 + hB];
  float ax = 0.f, ay = 0.f, az = 0.f, aw = 0.f, z = 0.f;
  int e = start + half;
  for (; e + 2 < end; e += 4) {
    int s0 = csr_src[e];
    int s1 = csr_src[e + 2];
    float a0 = as1[s0 * 4 + hB] + ad_b;
    float a1 = as1[s1 * 4 + hB] + ad_b;
    float4 g0 = loadh4(h1 + (size_t)s0 * 128 + 4 * c);
    float4 g1 = loadh4(h1 + (size_t)s1 * 128 + 4 * c);
    a0 = (a0 > 0.f) ? a0 : SLOPE * a0;
    a1 = (a1 > 0.f) ? a1 : SLOPE * a1;
    float w0 = __expf(a0), w1 = __expf(a1);
    ax += w0 * g0.x + w1 * g1.x;
    ay += w0 * g0.y + w1 * g1.y;
    az += w0 * g0.z + w1 * g1.z;
    aw += w0 * g0.w + w1 * g1.w;
    z += w0 + w1;
  }
  for (; e < end; e += 2) {
    int s = csr_src[e];
    float a = as1[s * 4 + hB] + ad_b;
    a = (a > 0.f) ? a : SLOPE * a;
    float w = __expf(a);
    float4 g = loadh4(h1 + (size_t)s * 128 + 4 * c);
    ax += w * g.x; ay += w * g.y; az += w * g.z; aw += w * g.w;
    z += w;
  }
  ax += __shfl_xor(ax, 32);
  ay += __shfl_xor(ay, 32);
  az += __shfl_xor(az, 32);
  aw += __shfl_xor(aw, 32);
  z += __shfl_xor(z, 32);
  if (half == 0) {
    float inv = 1.f / (z + GEPS);
    float4 bb = *(const float4*)(b1 + 4 * c);
    f16x4 o = {(f16)fmaxf(ax * inv + bb.x, 0.f),
               (f16)fmaxf(ay * inv + bb.y, 0.f),
               (f16)fmaxf(az * inv + bb.z, 0.f),
               (f16)fmaxf(aw * inv + bb.w, 0.f)};
    *(f16x4*)(out1 + (size_t)n * 128 + 4 * c) = o;
  }
}

// ---------------- layer-2 aggregation ----------------
__global__ __launch_bounds__(256) void gat2_kernel(
    const int* __restrict__ rowptr, const unsigned short* __restrict__ csr_src,
    const f16* __restrict__ h2, const float* __restrict__ as2,
    const float* __restrict__ ad2, const float* __restrict__ b2,
    float* __restrict__ out, int N) {
  int n = (blockIdx.x * 256 + threadIdx.x) >> 6;
  int l = threadIdx.x & 63;
  if (n >= N) return;
  int start = rowptr[n], end = rowptr[n + 1];
  int c = l & 15, q = l >> 4;
  float ad = ad2[n];
  float ax = 0.f, ay = 0.f, az = 0.f, aw = 0.f, z = 0.f;
  int e = start + q;
  for (; e + 4 < end; e += 8) {
    int s0 = csr_src[e];
    int s1 = csr_src[e + 4];
    float a0 = as2[s0] + ad;
    float a1 = as2[s1] + ad;
    float4 g0 = loadh4(h2 + (size_t)s0 * 64 + 4 * c);
    float4 g1 = loadh4(h2 + (size_t)s1 * 64 + 4 * c);
    a0 = (a0 > 0.f) ? a0 : SLOPE * a0;
    a1 = (a1 > 0.f) ? a1 : SLOPE * a1;
    float w0 = __expf(a0), w1 = __expf(a1);
    ax += w0 * g0.x + w1 * g1.x;
    ay += w0 * g0.y + w1 * g1.y;
    az += w0 * g0.z + w1 * g1.z;
    aw += w0 * g0.w + w1 * g1.w;
    z += w0 + w1;
  }
  for (; e < end; e += 4) {
    int s = csr_src[e];
    float a = as2[s] + ad;
    a = (a > 0.f) ? a : SLOPE * a;
    float w = __expf(a);
    float4 g = loadh4(h2 + (size_t)s * 64 + 4 * c);
    ax += w * g.x; ay += w * g.y; az += w * g.z; aw += w * g.w;
    z += w;
  }
  ax += __shfl_xor(ax, 16); ax += __shfl_xor(ax, 32);
  ay += __shfl_xor(ay, 16); ay += __shfl_xor(ay, 32);
  az += __shfl_xor(az, 16); az += __shfl_xor(az, 32);
  aw += __shfl_xor(aw, 16); aw += __shfl_xor(aw, 32);
  z += __shfl_xor(z, 16);  z += __shfl_xor(z, 32);
  if (q == 0) {
    float inv = 1.f / (z + GEPS);
    float4 bb = *(const float4*)(b2 + 4 * c);
    float4 o;
    o.x = fmaxf(ax * inv + bb.x, 0.f);
    o.y = fmaxf(ay * inv + bb.y, 0.f);
    o.z = fmaxf(az * inv + bb.z, 0.f);
    o.w = fmaxf(aw * inv + bb.w, 0.f);
    *(float4*)(out + (size_t)n * 64 + 4 * c) = o;
  }
}

extern "C" void kernel_launch(void* const* d_in, const int* in_sizes, int n_in,
                              void* d_out, int out_size, void* d_ws, size_t ws_size,
                              hipStream_t stream) {
  const float* x = (const float*)d_in[0];
  const int* ei = (const int*)d_in[1];
  const float* W1 = (const float*)d_in[2];
  const float* att_s1 = (const float*)d_in[3];
  const float* att_d1 = (const float*)d_in[4];
  const float* b1 = (const float*)d_in[5];
  const float* W2 = (const float*)d_in[6];
  const float* att_s2 = (const float*)d_in[7];
  const float* att_d2 = (const float*)d_in[8];
  const float* b2 = (const float*)d_in[9];
  float* out = (float*)d_out;

  char* ws = (char*)d_ws;
  size_t off = 0;
  auto alloc = [&](size_t bytes) {
    off = (off + 255) & ~(size_t)255;
    void* p = ws + off;
    off += bytes;
    return p;
  };
  int* deg = (int*)alloc((NN + 1) * sizeof(int));
  int* rowptr = (int*)alloc((NN + 1) * sizeof(int));
  int* cursor = (int*)alloc((size_t)NN * sizeof(int));
  int* bsum = (int*)alloc(NB * sizeof(int));
  int* boff = (int*)alloc(NB * sizeof(int));
  unsigned short* csr_src = (unsigned short*)alloc((size_t)ET * sizeof(unsigned short));
  f16* wt = (f16*)alloc(49152 * sizeof(f16));
  f16* h1 = (f16*)alloc((size_t)NN * 128 * sizeof(f16));
  float* as1 = (float*)alloc((size_t)NN * 4 * sizeof(float));
  float* ad1 = (float*)alloc((size_t)NN * 4 * sizeof(float));
  f16* out1h = (f16*)alloc((size_t)NN * 128 * sizeof(f16));
  f16* hh2 = h1;  // layer-2 features reuse h1 (dead after gat1)
  float* as2 = as1;
  float* ad2 = ad1;

  const int* src = ei;
  const int* dst = ei + NE;

  hipMemsetAsync(deg, 0, (NN + 1) * sizeof(int), stream);
  hipLaunchKernelGGL(wprep_kernel, dim3(96), dim3(256), 0, stream, W1, W2, wt);
  int qbks = (NQ + 255) / 256;
  hipLaunchKernelGGL(hist_kernel, dim3(qbks), dim3(256), 0, stream, dst, deg);
  hipLaunchKernelGGL(part_kernel, dim3(NB), dim3(256), 0, stream, deg, bsum);
  hipLaunchKernelGGL(bscan_kernel, dim3(1), dim3(256), 0, stream, bsum, boff);
  hipLaunchKernelGGL(rowptr_kernel, dim3(NB), dim3(256), 0, stream, deg, boff, rowptr,
                     cursor, csr_src);
  hipLaunchKernelGGL(scatter_kernel, dim3(qbks), dim3(256), 0, stream, src, dst, cursor,
                     csr_src);

  int rbks = (NN + 63) / 64;
  hipLaunchKernelGGL((mfma_gemm_kernel<128, true>), dim3(rbks, 2), dim3(256), 0, stream,
                     x, wt, wt + 16384, att_s1, att_d1, h1, as1, ad1, NN);
  hipLaunchKernelGGL(gat1_kernel, dim3((NN + 3) / 4), dim3(256), 0, stream, rowptr,
                     csr_src, h1, as1, ad1, b1, out1h, NN);

  hipLaunchKernelGGL((mfma_gemm_kernel<64, false>), dim3(rbks, 1), dim3(256), 0, stream,
                     out1h, wt + 32768, wt + 40960, att_s2, att_d2, hh2, as2, ad2, NN);
  hipLaunchKernelGGL(gat2_kernel, dim3((NN + 3) / 4), dim3(256), 0, stream, rowptr,
                     csr_src, hh2, as2, ad2, b2, out, NN);
}

// Round 8
// 144.143 us; speedup vs baseline: 4.2150x; 1.4042x over previous
//
#include <hip/hip_runtime.h>

#define NN 50000
#define NE 800000
#define ET (NE + NN)
#define SLOPE 0.2f
#define GEPS 1e-16f
#define NBUK 196     // ceil(NN/256) dst-buckets of 256 nodes
#define BCAP 8192    // per-bucket edge capacity (avg 4080, max ~4400)
#define CCHUNK 2048  // edges per partition block

typedef _Float16 f16;
typedef f16 f16x4 __attribute__((ext_vector_type(4)));
typedef f16 f16x8 __attribute__((ext_vector_type(8)));
typedef float f32x4 __attribute__((ext_vector_type(4)));

// ---------------- bucketed CSR build ----------------
__global__ __launch_bounds__(256) void binit_kernel(int* __restrict__ bcursor) {
  int t = threadIdx.x;
  if (t < NBUK) bcursor[t] = t * BCAP;
}

// partition edges into dst-buckets; block reserves contiguous ranges
__global__ __launch_bounds__(256) void bpart_kernel(const int* __restrict__ src,
                                                    const int* __restrict__ dst,
                                                    int* __restrict__ bcursor,
                                                    unsigned int* __restrict__ ebuf) {
  __shared__ int cnt[NBUK];
  __shared__ int ofs[NBUK];
  __shared__ int lcur[NBUK];
  int t = threadIdx.x;
  for (int i = t; i < NBUK; i += 256) {
    cnt[i] = 0;
    lcur[i] = 0;
  }
  __syncthreads();
  int base = blockIdx.x * CCHUNK;
  int nend = min(base + CCHUNK, NE);
  for (int i = base + t; i < nend; i += 256) atomicAdd(&cnt[dst[i] >> 8], 1);
  __syncthreads();
  for (int i = t; i < NBUK; i += 256)
    if (cnt[i] > 0) ofs[i] = atomicAdd(&bcursor[i], cnt[i]);
  __syncthreads();
  for (int i = base + t; i < nend; i += 256) {
    int d = dst[i];
    int s = src[i];
    int b = d >> 8;
    int p = ofs[b] + atomicAdd(&lcur[b], 1);
    ebuf[p] = ((unsigned)(d & 255) << 16) | (unsigned)s;
  }
}

// exclusive scan of per-bucket (edges + self-loops) -> csr_base
__global__ __launch_bounds__(256) void cscan_kernel(const int* __restrict__ bcursor,
                                                    int* __restrict__ csr_base,
                                                    int* __restrict__ rowptr) {
  __shared__ int lds[256];
  int t = threadIdx.x;
  int nodes = (t < NBUK) ? min(256, NN - t * 256) : 0;
  int v = (t < NBUK) ? (bcursor[t] - t * BCAP + nodes) : 0;
  lds[t] = v;
  __syncthreads();
  for (int off = 1; off < 256; off <<= 1) {
    int u = (t >= off) ? lds[t - off] : 0;
    __syncthreads();
    lds[t] += u;
    __syncthreads();
  }
  if (t < NBUK) csr_base[t] = lds[t] - v;
  if (t == 0) rowptr[NN] = ET;
}

// per-bucket CSR: degrees, rowptr, self-loop, edge scatter — all LDS cursors
__global__ __launch_bounds__(256) void bcsr_kernel(
    const unsigned int* __restrict__ ebuf, const int* __restrict__ bcursor,
    const int* __restrict__ csr_base, int* __restrict__ rowptr,
    unsigned short* __restrict__ csr) {
  __shared__ int deg[256];
  __shared__ int lcur[256];
  int b = blockIdx.x;
  int t = threadIdx.x;
  int ebase = b * BCAP;
  int count = bcursor[b] - ebase;
  int n0 = b * 256;
  int nodes = min(256, NN - n0);
  deg[t] = 0;
  __syncthreads();
  for (int i = t; i < count; i += 256)
    atomicAdd(&deg[ebuf[ebase + i] >> 16], 1);
  __syncthreads();
  int myv = (t < nodes) ? (deg[t] + 1) : 0;  // +1 self-loop
  __syncthreads();
  deg[t] = myv;
  __syncthreads();
  for (int off = 1; off < 256; off <<= 1) {
    int u = (t >= off) ? deg[t - off] : 0;
    __syncthreads();
    deg[t] += u;
    __syncthreads();
  }
  int cb = csr_base[b];
  if (t < nodes) {
    int excl = cb + deg[t] - myv;
    rowptr[n0 + t] = excl;
    csr[excl] = (unsigned short)(n0 + t);  // self-loop in slot 0
    lcur[t] = excl + 1;
  }
  __syncthreads();
  for (int i = t; i < count; i += 256) {
    unsigned e = ebuf[ebase + i];
    int p = atomicAdd(&lcur[e >> 16], 1);
    csr[p] = (unsigned short)(e & 0xFFFFu);
  }
}

// ---- W prep: split f32 W[K][NC] into hi/lo f16, transposed to [NC][K] ----
__global__ __launch_bounds__(256) void wprep_kernel(const float* __restrict__ W1,
                                                    const float* __restrict__ W2,
                                                    f16* __restrict__ wt) {
  int idx = blockIdx.x * 256 + threadIdx.x;
  if (idx < 16384) {
    int c = idx >> 7, k = idx & 127;
    float w = W1[k * 128 + c];
    f16 hi = (f16)w;
    f16 lo = (f16)(w - (float)hi);
    wt[c * 128 + k] = hi;
    wt[16384 + c * 128 + k] = lo;
  } else if (idx < 24576) {
    int i2 = idx - 16384;
    int c = i2 >> 7, k = i2 & 127;
    float w = W2[k * 64 + c];
    f16 hi = (f16)w;
    f16 lo = (f16)(w - (float)hi);
    wt[32768 + c * 128 + k] = hi;
    wt[40960 + c * 128 + k] = lo;
  }
}

// ---- MFMA GEMM + fused att dots: H(f16) = A(N x 128) @ W(128 x NC) ----
template <int NC, bool AF32>
__global__ __launch_bounds__(256) void mfma_gemm_kernel(
    const void* __restrict__ Av, const f16* __restrict__ whi,
    const f16* __restrict__ wlo, const float* __restrict__ atts,
    const float* __restrict__ attd, f16* __restrict__ Hh,
    float* __restrict__ a_s, float* __restrict__ a_d, int N) {
  constexpr int K = 128, BM = 64, KP = K + 8;
  __shared__ f16 Ah[BM * KP];
  __shared__ f16 Wh[64 * KP];
  __shared__ f16 Wl[64 * KP];
  const int tid = threadIdx.x;
  const int row0 = blockIdx.x * BM;
  const int col0 = blockIdx.y * 64;
  if (AF32) {
    const float* A = (const float*)Av;
#pragma unroll
    for (int j = 0; j < 8; ++j) {
      int idx = j * 256 + tid;
      int r = idx >> 5, col = (idx & 31) << 2;
      int gr = row0 + r;
      float4 v = make_float4(0.f, 0.f, 0.f, 0.f);
      if (gr < N) v = *(const float4*)(A + (size_t)gr * K + col);
      f16x4 hv = {(f16)v.x, (f16)v.y, (f16)v.z, (f16)v.w};
      *(f16x4*)&Ah[r * KP + col] = hv;
    }
  } else {
    const f16* A = (const f16*)Av;
#pragma unroll
    for (int j = 0; j < 4; ++j) {
      int idx = j * 256 + tid;
      int r = idx >> 4, col = (idx & 15) << 3;
      int gr = row0 + r;
      f16x8 v = {};
      if (gr < N) v = *(const f16x8*)(A + (size_t)gr * K + col);
      *(f16x8*)&Ah[r * KP + col] = v;
    }
  }
#pragma unroll
  for (int j = 0; j < 4; ++j) {
    int idx = j * 256 + tid;
    int r = idx >> 4, col = (idx & 15) << 3;
    *(f16x8*)&Wh[r * KP + col] =
        *(const f16x8*)(whi + (size_t)(col0 + r) * K + col);
    *(f16x8*)&Wl[r * KP + col] =
        *(const f16x8*)(wlo + (size_t)(col0 + r) * K + col);
  }
  __syncthreads();
  const int lane = tid & 63;
  const int w = tid >> 6;
  const int lr = lane & 15;
  const int lk = (lane >> 4) << 3;
  f32x4 acc[4];
#pragma unroll
  for (int cf = 0; cf < 4; ++cf) acc[cf] = (f32x4){0.f, 0.f, 0.f, 0.f};
  const f16* arow = Ah + (w * 16 + lr) * KP + lk;
  const f16* bhrow = Wh + lr * KP + lk;
  const f16* blrow = Wl + lr * KP + lk;
#pragma unroll
  for (int ks = 0; ks < 4; ++ks) {
    int k0 = ks * 32;
    f16x8 af = *(const f16x8*)(arow + k0);
#pragma unroll
    for (int cf = 0; cf < 4; ++cf) {
      f16x8 bh = *(const f16x8*)(bhrow + cf * 16 * KP + k0);
      f16x8 bl = *(const f16x8*)(blrow + cf * 16 * KP + k0);
      acc[cf] = __builtin_amdgcn_mfma_f32_16x16x32_f16(af, bh, acc[cf], 0, 0, 0);
      acc[cf] = __builtin_amdgcn_mfma_f32_16x16x32_f16(af, bl, acc[cf], 0, 0, 0);
    }
  }
  const int rbase = row0 + w * 16 + ((lane >> 4) << 2);
#pragma unroll
  for (int cf = 0; cf < 4; ++cf) {
    int col = col0 + cf * 16 + lr;
#pragma unroll
    for (int r4 = 0; r4 < 4; ++r4) {
      int gr = rbase + r4;
      if (gr < N) Hh[(size_t)gr * NC + col] = (f16)acc[cf][r4];
    }
  }
  float asc[4], adc[4];
#pragma unroll
  for (int cf = 0; cf < 4; ++cf) {
    asc[cf] = atts[col0 + cf * 16 + lr];
    adc[cf] = attd[col0 + cf * 16 + lr];
  }
  if (NC == 128) {
#pragma unroll
    for (int m = 0; m < 2; ++m) {
#pragma unroll
      for (int r4 = 0; r4 < 4; ++r4) {
        float sp = acc[2 * m][r4] * asc[2 * m] + acc[2 * m + 1][r4] * asc[2 * m + 1];
        float dp = acc[2 * m][r4] * adc[2 * m] + acc[2 * m + 1][r4] * adc[2 * m + 1];
        sp += __shfl_xor(sp, 1); sp += __shfl_xor(sp, 2);
        sp += __shfl_xor(sp, 4); sp += __shfl_xor(sp, 8);
        dp += __shfl_xor(dp, 1); dp += __shfl_xor(dp, 2);
        dp += __shfl_xor(dp, 4); dp += __shfl_xor(dp, 8);
        int gr = rbase + r4;
        if (lr == 0 && gr < N) {
          int hd = blockIdx.y * 2 + m;
          a_s[gr * 4 + hd] = sp;
          a_d[gr * 4 + hd] = dp;
        }
      }
    }
  } else {
#pragma unroll
    for (int r4 = 0; r4 < 4; ++r4) {
      float sp = acc[0][r4] * asc[0] + acc[1][r4] * asc[1] +
                 acc[2][r4] * asc[2] + acc[3][r4] * asc[3];
      float dp = acc[0][r4] * adc[0] + acc[1][r4] * adc[1] +
                 acc[2][r4] * adc[2] + acc[3][r4] * adc[3];
      sp += __shfl_xor(sp, 1); sp += __shfl_xor(sp, 2);
      sp += __shfl_xor(sp, 4); sp += __shfl_xor(sp, 8);
      dp += __shfl_xor(dp, 1); dp += __shfl_xor(dp, 2);
      dp += __shfl_xor(dp, 4); dp += __shfl_xor(dp, 8);
      int gr = rbase + r4;
      if (lr == 0 && gr < N) {
        a_s[gr] = sp;
        a_d[gr] = dp;
      }
    }
  }
}

__device__ inline float4 loadh4(const f16* p) {
  f16x4 h = *(const f16x4*)p;
  return make_float4((float)h[0], (float)h[1], (float)h[2], (float)h[3]);
}

// ---------------- layer-1 aggregation (out f16 for gemm2) ----------------
__global__ __launch_bounds__(256) void gat1_kernel(
    const int* __restrict__ rowptr, const unsigned short* __restrict__ csr_src,
    const f16* __restrict__ h1, const float* __restrict__ as1,
    const float* __restrict__ ad1, const float* __restrict__ b1,
    f16* __restrict__ out1, int N) {
  int n = (blockIdx.x * 256 + threadIdx.x) >> 6;
  int l = threadIdx.x & 63;
  if (n >= N) return;
  int start = rowptr[n], end = rowptr[n + 1];
  int c = l & 31, half = l >> 5;
  int hB = c >> 3;
  float ad_b = ad1[n * 4 + hB];
  float ax = 0.f, ay = 0.f, az = 0.f, aw = 0.f, z = 0.f;
  int e = start + half;
  for (; e + 2 < end; e += 4) {
    int s0 = csr_src[e];
    int s1 = csr_src[e + 2];
    float a0 = as1[s0 * 4 + hB] + ad_b;
    float a1 = as1[s1 * 4 + hB] + ad_b;
    float4 g0 = loadh4(h1 + (size_t)s0 * 128 + 4 * c);
    float4 g1 = loadh4(h1 + (size_t)s1 * 128 + 4 * c);
    a0 = (a0 > 0.f) ? a0 : SLOPE * a0;
    a1 = (a1 > 0.f) ? a1 : SLOPE * a1;
    float w0 = __expf(a0), w1 = __expf(a1);
    ax += w0 * g0.x + w1 * g1.x;
    ay += w0 * g0.y + w1 * g1.y;
    az += w0 * g0.z + w1 * g1.z;
    aw += w0 * g0.w + w1 * g1.w;
    z += w0 + w1;
  }
  for (; e < end; e += 2) {
    int s = csr_src[e];
    float a = as1[s * 4 + hB] + ad_b;
    a = (a > 0.f) ? a : SLOPE * a;
    float w = __expf(a);
    float4 g = loadh4(h1 + (size_t)s * 128 + 4 * c);
    ax += w * g.x; ay += w * g.y; az += w * g.z; aw += w * g.w;
    z += w;
  }
  ax += __shfl_xor(ax, 32);
  ay += __shfl_xor(ay, 32);
  az += __shfl_xor(az, 32);
  aw += __shfl_xor(aw, 32);
  z += __shfl_xor(z, 32);
  if (half == 0) {
    float inv = 1.f / (z + GEPS);
    float4 bb = *(const float4*)(b1 + 4 * c);
    f16x4 o = {(f16)fmaxf(ax * inv + bb.x, 0.f),
               (f16)fmaxf(ay * inv + bb.y, 0.f),
               (f16)fmaxf(az * inv + bb.z, 0.f),
               (f16)fmaxf(aw * inv + bb.w, 0.f)};
    *(f16x4*)(out1 + (size_t)n * 128 + 4 * c) = o;
  }
}

// ---------------- layer-2 aggregation ----------------
__global__ __launch_bounds__(256) void gat2_kernel(
    const int* __restrict__ rowptr, const unsigned short* __restrict__ csr_src,
    const f16* __restrict__ h2, const float* __restrict__ as2,
    const float* __restrict__ ad2, const float* __restrict__ b2,
    float* __restrict__ out, int N) {
  int n = (blockIdx.x * 256 + threadIdx.x) >> 6;
  int l = threadIdx.x & 63;
  if (n >= N) return;
  int start = rowptr[n], end = rowptr[n + 1];
  int c = l & 15, q = l >> 4;
  float ad = ad2[n];
  float ax = 0.f, ay = 0.f, az = 0.f, aw = 0.f, z = 0.f;
  int e = start + q;
  for (; e + 4 < end; e += 8) {
    int s0 = csr_src[e];
    int s1 = csr_src[e + 4];
    float a0 = as2[s0] + ad;
    float a1 = as2[s1] + ad;
    float4 g0 = loadh4(h2 + (size_t)s0 * 64 + 4 * c);
    float4 g1 = loadh4(h2 + (size_t)s1 * 64 + 4 * c);
    a0 = (a0 > 0.f) ? a0 : SLOPE * a0;
    a1 = (a1 > 0.f) ? a1 : SLOPE * a1;
    float w0 = __expf(a0), w1 = __expf(a1);
    ax += w0 * g0.x + w1 * g1.x;
    ay += w0 * g0.y + w1 * g1.y;
    az += w0 * g0.z + w1 * g1.z;
    aw += w0 * g0.w + w1 * g1.w;
    z += w0 + w1;
  }
  for (; e < end; e += 4) {
    int s = csr_src[e];
    float a = as2[s] + ad;
    a = (a > 0.f) ? a : SLOPE * a;
    float w = __expf(a);
    float4 g = loadh4(h2 + (size_t)s * 64 + 4 * c);
    ax += w * g.x; ay += w * g.y; az += w * g.z; aw += w * g.w;
    z += w;
  }
  ax += __shfl_xor(ax, 16); ax += __shfl_xor(ax, 32);
  ay += __shfl_xor(ay, 16); ay += __shfl_xor(ay, 32);
  az += __shfl_xor(az, 16); az += __shfl_xor(az, 32);
  aw += __shfl_xor(aw, 16); aw += __shfl_xor(aw, 32);
  z += __shfl_xor(z, 16);  z += __shfl_xor(z, 32);
  if (q == 0) {
    float inv = 1.f / (z + GEPS);
    float4 bb = *(const float4*)(b2 + 4 * c);
    float4 o;
    o.x = fmaxf(ax * inv + bb.x, 0.f);
    o.y = fmaxf(ay * inv + bb.y, 0.f);
    o.z = fmaxf(az * inv + bb.z, 0.f);
    o.w = fmaxf(aw * inv + bb.w, 0.f);
    *(float4*)(out + (size_t)n * 64 + 4 * c) = o;
  }
}

extern "C" void kernel_launch(void* const* d_in, const int* in_sizes, int n_in,
                              void* d_out, int out_size, void* d_ws, size_t ws_size,
                              hipStream_t stream) {
  const float* x = (const float*)d_in[0];
  const int* ei = (const int*)d_in[1];
  const float* W1 = (const float*)d_in[2];
  const float* att_s1 = (const float*)d_in[3];
  const float* att_d1 = (const float*)d_in[4];
  const float* b1 = (const float*)d_in[5];
  const float* W2 = (const float*)d_in[6];
  const float* att_s2 = (const float*)d_in[7];
  const float* att_d2 = (const float*)d_in[8];
  const float* b2 = (const float*)d_in[9];
  float* out = (float*)d_out;

  char* ws = (char*)d_ws;
  size_t off = 0;
  auto alloc = [&](size_t bytes) {
    off = (off + 255) & ~(size_t)255;
    void* p = ws + off;
    off += bytes;
    return p;
  };
  int* bcursor = (int*)alloc(NBUK * sizeof(int));
  int* csr_base = (int*)alloc(NBUK * sizeof(int));
  unsigned int* ebuf = (unsigned int*)alloc((size_t)NBUK * BCAP * sizeof(unsigned int));
  int* rowptr = (int*)alloc((NN + 1) * sizeof(int));
  unsigned short* csr_src = (unsigned short*)alloc((size_t)ET * sizeof(unsigned short));
  f16* wt = (f16*)alloc(49152 * sizeof(f16));
  f16* h1 = (f16*)alloc((size_t)NN * 128 * sizeof(f16));
  float* as1 = (float*)alloc((size_t)NN * 4 * sizeof(float));
  float* ad1 = (float*)alloc((size_t)NN * 4 * sizeof(float));
  f16* out1h = (f16*)alloc((size_t)NN * 128 * sizeof(f16));
  f16* hh2 = h1;  // layer-2 features reuse h1 (dead after gat1)
  float* as2 = as1;
  float* ad2 = ad1;

  const int* src = ei;
  const int* dst = ei + NE;

  hipLaunchKernelGGL(wprep_kernel, dim3(96), dim3(256), 0, stream, W1, W2, wt);
  hipLaunchKernelGGL(binit_kernel, dim3(1), dim3(256), 0, stream, bcursor);
  hipLaunchKernelGGL(bpart_kernel, dim3((NE + CCHUNK - 1) / CCHUNK), dim3(256), 0,
                     stream, src, dst, bcursor, ebuf);
  hipLaunchKernelGGL(cscan_kernel, dim3(1), dim3(256), 0, stream, bcursor, csr_base,
                     rowptr);
  hipLaunchKernelGGL(bcsr_kernel, dim3(NBUK), dim3(256), 0, stream, ebuf, bcursor,
                     csr_base, rowptr, csr_src);

  int rbks = (NN + 63) / 64;
  hipLaunchKernelGGL((mfma_gemm_kernel<128, true>), dim3(rbks, 2), dim3(256), 0, stream,
                     x, wt, wt + 16384, att_s1, att_d1, h1, as1, ad1, NN);
  hipLaunchKernelGGL(gat1_kernel, dim3((NN + 3) / 4), dim3(256), 0, stream, rowptr,
                     csr_src, h1, as1, ad1, b1, out1h, NN);

  hipLaunchKernelGGL((mfma_gemm_kernel<64, false>), dim3(rbks, 1), dim3(256), 0, stream,
                     out1h, wt + 32768, wt + 40960, att_s2, att_d2, hh2, as2, ad2, NN);
  hipLaunchKernelGGL(gat2_kernel, dim3((NN + 3) / 4), dim3(256), 0, stream, rowptr,
                     csr_src, hh2, as2, ad2, b2, out, NN);
}

// Round 9
// 133.921 us; speedup vs baseline: 4.5367x; 1.0763x over previous
//
#include <hip/hip_runtime.h>

#define NN 50000
#define NE 800000
#define ET (NE + NN)
#define SLOPE 0.2f
#define GEPS 1e-16f
#define NBUK 196     // ceil(NN/256) dst-buckets of 256 nodes
#define BCAP 8192    // per-bucket edge capacity (avg 4080, max ~4400)
#define CCHUNK 2048  // edges per partition block

typedef _Float16 f16;
typedef f16 f16x4 __attribute__((ext_vector_type(4)));
typedef f16 f16x8 __attribute__((ext_vector_type(8)));
typedef float f32x4 __attribute__((ext_vector_type(4)));

// ---------------- bucketed CSR build ----------------
__global__ __launch_bounds__(256) void binit_kernel(int* __restrict__ bcursor) {
  int t = threadIdx.x;
  if (t < NBUK) bcursor[t] = t * BCAP;
}

__global__ __launch_bounds__(256) void bpart_kernel(const int* __restrict__ src,
                                                    const int* __restrict__ dst,
                                                    int* __restrict__ bcursor,
                                                    unsigned int* __restrict__ ebuf) {
  __shared__ int cnt[NBUK];
  __shared__ int ofs[NBUK];
  __shared__ int lcur[NBUK];
  int t = threadIdx.x;
  for (int i = t; i < NBUK; i += 256) {
    cnt[i] = 0;
    lcur[i] = 0;
  }
  __syncthreads();
  int base = blockIdx.x * CCHUNK;
  int nend = min(base + CCHUNK, NE);
  for (int i = base + t; i < nend; i += 256) atomicAdd(&cnt[dst[i] >> 8], 1);
  __syncthreads();
  for (int i = t; i < NBUK; i += 256)
    if (cnt[i] > 0) ofs[i] = atomicAdd(&bcursor[i], cnt[i]);
  __syncthreads();
  for (int i = base + t; i < nend; i += 256) {
    int d = dst[i];
    int s = src[i];
    int b = d >> 8;
    int p = ofs[b] + atomicAdd(&lcur[b], 1);
    ebuf[p] = ((unsigned)(d & 255) << 16) | (unsigned)s;
  }
}

__global__ __launch_bounds__(256) void cscan_kernel(const int* __restrict__ bcursor,
                                                    int* __restrict__ csr_base,
                                                    int* __restrict__ rowptr) {
  __shared__ int lds[256];
  int t = threadIdx.x;
  int nodes = (t < NBUK) ? min(256, NN - t * 256) : 0;
  int v = (t < NBUK) ? (bcursor[t] - t * BCAP + nodes) : 0;
  lds[t] = v;
  __syncthreads();
  for (int off = 1; off < 256; off <<= 1) {
    int u = (t >= off) ? lds[t - off] : 0;
    __syncthreads();
    lds[t] += u;
    __syncthreads();
  }
  if (t < NBUK) csr_base[t] = lds[t] - v;
  if (t == 0) rowptr[NN] = ET;
}

__global__ __launch_bounds__(256) void bcsr_kernel(
    const unsigned int* __restrict__ ebuf, const int* __restrict__ bcursor,
    const int* __restrict__ csr_base, int* __restrict__ rowptr,
    unsigned short* __restrict__ csr) {
  __shared__ int deg[256];
  __shared__ int lcur[256];
  int b = blockIdx.x;
  int t = threadIdx.x;
  int ebase = b * BCAP;
  int count = bcursor[b] - ebase;
  int n0 = b * 256;
  int nodes = min(256, NN - n0);
  deg[t] = 0;
  __syncthreads();
  for (int i = t; i < count; i += 256)
    atomicAdd(&deg[ebuf[ebase + i] >> 16], 1);
  __syncthreads();
  int myv = (t < nodes) ? (deg[t] + 1) : 0;  // +1 self-loop
  __syncthreads();
  deg[t] = myv;
  __syncthreads();
  for (int off = 1; off < 256; off <<= 1) {
    int u = (t >= off) ? deg[t - off] : 0;
    __syncthreads();
    deg[t] += u;
    __syncthreads();
  }
  int cb = csr_base[b];
  if (t < nodes) {
    int excl = cb + deg[t] - myv;
    rowptr[n0 + t] = excl;
    csr[excl] = (unsigned short)(n0 + t);  // self-loop in slot 0
    lcur[t] = excl + 1;
  }
  __syncthreads();
  for (int i = t; i < count; i += 256) {
    unsigned e = ebuf[ebase + i];
    int p = atomicAdd(&lcur[e >> 16], 1);
    csr[p] = (unsigned short)(e & 0xFFFFu);
  }
}

// ---- W prep: split f32 W[K][NC] into hi/lo f16, transposed to [NC][K] ----
__global__ __launch_bounds__(256) void wprep_kernel(const float* __restrict__ W1,
                                                    const float* __restrict__ W2,
                                                    f16* __restrict__ wt) {
  int idx = blockIdx.x * 256 + threadIdx.x;
  if (idx < 16384) {
    int c = idx >> 7, k = idx & 127;
    float w = W1[k * 128 + c];
    f16 hi = (f16)w;
    f16 lo = (f16)(w - (float)hi);
    wt[c * 128 + k] = hi;
    wt[16384 + c * 128 + k] = lo;
  } else if (idx < 24576) {
    int i2 = idx - 16384;
    int c = i2 >> 7, k = i2 & 127;
    float w = W2[k * 64 + c];
    f16 hi = (f16)w;
    f16 lo = (f16)(w - (float)hi);
    wt[32768 + c * 128 + k] = hi;
    wt[40960 + c * 128 + k] = lo;
  }
}

// ---- MFMA GEMM + fused att dots: H(f16) = A(N x 128) @ W(128 x NC) ----
template <int NC, bool AF32>
__global__ __launch_bounds__(256) void mfma_gemm_kernel(
    const void* __restrict__ Av, const f16* __restrict__ whi,
    const f16* __restrict__ wlo, const float* __restrict__ atts,
    const float* __restrict__ attd, f16* __restrict__ Hh,
    float* __restrict__ a_s, float* __restrict__ a_d, int N) {
  constexpr int K = 128, BM = 64, KP = K + 8;
  __shared__ f16 Ah[BM * KP];
  __shared__ f16 Wh[64 * KP];
  __shared__ f16 Wl[64 * KP];
  const int tid = threadIdx.x;
  const int row0 = blockIdx.x * BM;
  const int col0 = blockIdx.y * 64;
  if (AF32) {
    const float* A = (const float*)Av;
#pragma unroll
    for (int j = 0; j < 8; ++j) {
      int idx = j * 256 + tid;
      int r = idx >> 5, col = (idx & 31) << 2;
      int gr = row0 + r;
      float4 v = make_float4(0.f, 0.f, 0.f, 0.f);
      if (gr < N) v = *(const float4*)(A + (size_t)gr * K + col);
      f16x4 hv = {(f16)v.x, (f16)v.y, (f16)v.z, (f16)v.w};
      *(f16x4*)&Ah[r * KP + col] = hv;
    }
  } else {
    const f16* A = (const f16*)Av;
#pragma unroll
    for (int j = 0; j < 4; ++j) {
      int idx = j * 256 + tid;
      int r = idx >> 4, col = (idx & 15) << 3;
      int gr = row0 + r;
      f16x8 v = {};
      if (gr < N) v = *(const f16x8*)(A + (size_t)gr * K + col);
      *(f16x8*)&Ah[r * KP + col] = v;
    }
  }
#pragma unroll
  for (int j = 0; j < 4; ++j) {
    int idx = j * 256 + tid;
    int r = idx >> 4, col = (idx & 15) << 3;
    *(f16x8*)&Wh[r * KP + col] =
        *(const f16x8*)(whi + (size_t)(col0 + r) * K + col);
    *(f16x8*)&Wl[r * KP + col] =
        *(const f16x8*)(wlo + (size_t)(col0 + r) * K + col);
  }
  __syncthreads();
  const int lane = tid & 63;
  const int w = tid >> 6;
  const int lr = lane & 15;
  const int lk = (lane >> 4) << 3;
  f32x4 acc[4];
#pragma unroll
  for (int cf = 0; cf < 4; ++cf) acc[cf] = (f32x4){0.f, 0.f, 0.f, 0.f};
  const f16* arow = Ah + (w * 16 + lr) * KP + lk;
  const f16* bhrow = Wh + lr * KP + lk;
  const f16* blrow = Wl + lr * KP + lk;
#pragma unroll
  for (int ks = 0; ks < 4; ++ks) {
    int k0 = ks * 32;
    f16x8 af = *(const f16x8*)(arow + k0);
#pragma unroll
    for (int cf = 0; cf < 4; ++cf) {
      f16x8 bh = *(const f16x8*)(bhrow + cf * 16 * KP + k0);
      f16x8 bl = *(const f16x8*)(blrow + cf * 16 * KP + k0);
      acc[cf] = __builtin_amdgcn_mfma_f32_16x16x32_f16(af, bh, acc[cf], 0, 0, 0);
      acc[cf] = __builtin_amdgcn_mfma_f32_16x16x32_f16(af, bl, acc[cf], 0, 0, 0);
    }
  }
  const int rbase = row0 + w * 16 + ((lane >> 4) << 2);
#pragma unroll
  for (int cf = 0; cf < 4; ++cf) {
    int col = col0 + cf * 16 + lr;
#pragma unroll
    for (int r4 = 0; r4 < 4; ++r4) {
      int gr = rbase + r4;
      if (gr < N) Hh[(size_t)gr * NC + col] = (f16)acc[cf][r4];
    }
  }
  float asc[4], adc[4];
#pragma unroll
  for (int cf = 0; cf < 4; ++cf) {
    asc[cf] = atts[col0 + cf * 16 + lr];
    adc[cf] = attd[col0 + cf * 16 + lr];
  }
  if (NC == 128) {
#pragma unroll
    for (int m = 0; m < 2; ++m) {
#pragma unroll
      for (int r4 = 0; r4 < 4; ++r4) {
        float sp = acc[2 * m][r4] * asc[2 * m] + acc[2 * m + 1][r4] * asc[2 * m + 1];
        float dp = acc[2 * m][r4] * adc[2 * m] + acc[2 * m + 1][r4] * adc[2 * m + 1];
        sp += __shfl_xor(sp, 1); sp += __shfl_xor(sp, 2);
        sp += __shfl_xor(sp, 4); sp += __shfl_xor(sp, 8);
        dp += __shfl_xor(dp, 1); dp += __shfl_xor(dp, 2);
        dp += __shfl_xor(dp, 4); dp += __shfl_xor(dp, 8);
        int gr = rbase + r4;
        if (lr == 0 && gr < N) {
          int hd = blockIdx.y * 2 + m;
          a_s[gr * 4 + hd] = sp;
          a_d[gr * 4 + hd] = dp;
        }
      }
    }
  } else {
#pragma unroll
    for (int r4 = 0; r4 < 4; ++r4) {
      float sp = acc[0][r4] * asc[0] + acc[1][r4] * asc[1] +
                 acc[2][r4] * asc[2] + acc[3][r4] * asc[3];
      float dp = acc[0][r4] * adc[0] + acc[1][r4] * adc[1] +
                 acc[2][r4] * adc[2] + acc[3][r4] * adc[3];
      sp += __shfl_xor(sp, 1); sp += __shfl_xor(sp, 2);
      sp += __shfl_xor(sp, 4); sp += __shfl_xor(sp, 8);
      dp += __shfl_xor(dp, 1); dp += __shfl_xor(dp, 2);
      dp += __shfl_xor(dp, 4); dp += __shfl_xor(dp, 8);
      int gr = rbase + r4;
      if (lr == 0 && gr < N) {
        a_s[gr] = sp;
        a_d[gr] = dp;
      }
    }
  }
}

// ---------------- layer-1 aggregation: 16 lanes/edge, 4 edges/iter ----------------
__global__ __launch_bounds__(256) void gat1_kernel(
    const int* __restrict__ rowptr, const unsigned short* __restrict__ csr_src,
    const f16* __restrict__ h1, const float* __restrict__ as1,
    const float* __restrict__ ad1, const float* __restrict__ b1,
    f16* __restrict__ out1, int N) {
  int n = (blockIdx.x * 256 + threadIdx.x) >> 6;
  int l = threadIdx.x & 63;
  if (n >= N) return;
  int start = rowptr[n], end = rowptr[n + 1];
  int c = l & 15, q = l >> 4;  // lane c: channels 8c..8c+7; quarter q: edge slot
  int hB = c >> 2;             // head of this 8-channel group
  float ad_b = ad1[n * 4 + hB];
  float acc[8] = {0.f, 0.f, 0.f, 0.f, 0.f, 0.f, 0.f, 0.f};
  float z = 0.f;
  int e = start + q;
  for (; e + 4 < end; e += 8) {
    int s0 = csr_src[e];
    int s1 = csr_src[e + 4];
    float a0 = as1[s0 * 4 + hB] + ad_b;
    float a1 = as1[s1 * 4 + hB] + ad_b;
    f16x8 g0 = *(const f16x8*)(h1 + (size_t)s0 * 128 + 8 * c);
    f16x8 g1 = *(const f16x8*)(h1 + (size_t)s1 * 128 + 8 * c);
    a0 = (a0 > 0.f) ? a0 : SLOPE * a0;
    a1 = (a1 > 0.f) ? a1 : SLOPE * a1;
    float w0 = __expf(a0), w1 = __expf(a1);
#pragma unroll
    for (int j = 0; j < 8; ++j)
      acc[j] += w0 * (float)g0[j] + w1 * (float)g1[j];
    z += w0 + w1;
  }
  for (; e < end; e += 4) {
    int s = csr_src[e];
    float a = as1[s * 4 + hB] + ad_b;
    a = (a > 0.f) ? a : SLOPE * a;
    float w = __expf(a);
    f16x8 g = *(const f16x8*)(h1 + (size_t)s * 128 + 8 * c);
#pragma unroll
    for (int j = 0; j < 8; ++j) acc[j] += w * (float)g[j];
    z += w;
  }
#pragma unroll
  for (int j = 0; j < 8; ++j) {
    acc[j] += __shfl_xor(acc[j], 16);
    acc[j] += __shfl_xor(acc[j], 32);
  }
  z += __shfl_xor(z, 16);
  z += __shfl_xor(z, 32);
  if (q == 0) {
    float inv = 1.f / (z + GEPS);
    float4 bb0 = *(const float4*)(b1 + 8 * c);
    float4 bb1 = *(const float4*)(b1 + 8 * c + 4);
    f16x8 o;
    o[0] = (f16)fmaxf(acc[0] * inv + bb0.x, 0.f);
    o[1] = (f16)fmaxf(acc[1] * inv + bb0.y, 0.f);
    o[2] = (f16)fmaxf(acc[2] * inv + bb0.z, 0.f);
    o[3] = (f16)fmaxf(acc[3] * inv + bb0.w, 0.f);
    o[4] = (f16)fmaxf(acc[4] * inv + bb1.x, 0.f);
    o[5] = (f16)fmaxf(acc[5] * inv + bb1.y, 0.f);
    o[6] = (f16)fmaxf(acc[6] * inv + bb1.z, 0.f);
    o[7] = (f16)fmaxf(acc[7] * inv + bb1.w, 0.f);
    *(f16x8*)(out1 + (size_t)n * 128 + 8 * c) = o;
  }
}

// ---------------- layer-2 aggregation: 8 lanes/edge, 8 edges/iter ----------------
__global__ __launch_bounds__(256) void gat2_kernel(
    const int* __restrict__ rowptr, const unsigned short* __restrict__ csr_src,
    const f16* __restrict__ h2, const float* __restrict__ as2,
    const float* __restrict__ ad2, const float* __restrict__ b2,
    float* __restrict__ out, int N) {
  int n = (blockIdx.x * 256 + threadIdx.x) >> 6;
  int l = threadIdx.x & 63;
  if (n >= N) return;
  int start = rowptr[n], end = rowptr[n + 1];
  int c = l & 7, q = l >> 3;  // lane c: channels 8c..8c+7; q: edge slot 0..7
  float ad = ad2[n];
  float acc[8] = {0.f, 0.f, 0.f, 0.f, 0.f, 0.f, 0.f, 0.f};
  float z = 0.f;
  int e = start + q;
  for (; e + 8 < end; e += 16) {
    int s0 = csr_src[e];
    int s1 = csr_src[e + 8];
    float a0 = as2[s0] + ad;
    float a1 = as2[s1] + ad;
    f16x8 g0 = *(const f16x8*)(h2 + (size_t)s0 * 64 + 8 * c);
    f16x8 g1 = *(const f16x8*)(h2 + (size_t)s1 * 64 + 8 * c);
    a0 = (a0 > 0.f) ? a0 : SLOPE * a0;
    a1 = (a1 > 0.f) ? a1 : SLOPE * a1;
    float w0 = __expf(a0), w1 = __expf(a1);
#pragma unroll
    for (int j = 0; j < 8; ++j)
      acc[j] += w0 * (float)g0[j] + w1 * (float)g1[j];
    z += w0 + w1;
  }
  for (; e < end; e += 8) {
    int s = csr_src[e];
    float a = as2[s] + ad;
    a = (a > 0.f) ? a : SLOPE * a;
    float w = __expf(a);
    f16x8 g = *(const f16x8*)(h2 + (size_t)s * 64 + 8 * c);
#pragma unroll
    for (int j = 0; j < 8; ++j) acc[j] += w * (float)g[j];
    z += w;
  }
#pragma unroll
  for (int j = 0; j < 8; ++j) {
    acc[j] += __shfl_xor(acc[j], 8);
    acc[j] += __shfl_xor(acc[j], 16);
    acc[j] += __shfl_xor(acc[j], 32);
  }
  z += __shfl_xor(z, 8);
  z += __shfl_xor(z, 16);
  z += __shfl_xor(z, 32);
  if (q == 0) {
    float inv = 1.f / (z + GEPS);
    float4 bb0 = *(const float4*)(b2 + 8 * c);
    float4 bb1 = *(const float4*)(b2 + 8 * c + 4);
    float4 o0, o1;
    o0.x = fmaxf(acc[0] * inv + bb0.x, 0.f);
    o0.y = fmaxf(acc[1] * inv + bb0.y, 0.f);
    o0.z = fmaxf(acc[2] * inv + bb0.z, 0.f);
    o0.w = fmaxf(acc[3] * inv + bb0.w, 0.f);
    o1.x = fmaxf(acc[4] * inv + bb1.x, 0.f);
    o1.y = fmaxf(acc[5] * inv + bb1.y, 0.f);
    o1.z = fmaxf(acc[6] * inv + bb1.z, 0.f);
    o1.w = fmaxf(acc[7] * inv + bb1.w, 0.f);
    *(float4*)(out + (size_t)n * 64 + 8 * c) = o0;
    *(float4*)(out + (size_t)n * 64 + 8 * c + 4) = o1;
  }
}

extern "C" void kernel_launch(void* const* d_in, const int* in_sizes, int n_in,
                              void* d_out, int out_size, void* d_ws, size_t ws_size,
                              hipStream_t stream) {
  const float* x = (const float*)d_in[0];
  const int* ei = (const int*)d_in[1];
  const float* W1 = (const float*)d_in[2];
  const float* att_s1 = (const float*)d_in[3];
  const float* att_d1 = (const float*)d_in[4];
  const float* b1 = (const float*)d_in[5];
  const float* W2 = (const float*)d_in[6];
  const float* att_s2 = (const float*)d_in[7];
  const float* att_d2 = (const float*)d_in[8];
  const float* b2 = (const float*)d_in[9];
  float* out = (float*)d_out;

  char* ws = (char*)d_ws;
  size_t off = 0;
  auto alloc = [&](size_t bytes) {
    off = (off + 255) & ~(size_t)255;
    void* p = ws + off;
    off += bytes;
    return p;
  };
  int* bcursor = (int*)alloc(NBUK * sizeof(int));
  int* csr_base = (int*)alloc(NBUK * sizeof(int));
  unsigned int* ebuf = (unsigned int*)alloc((size_t)NBUK * BCAP * sizeof(unsigned int));
  int* rowptr = (int*)alloc((NN + 1) * sizeof(int));
  unsigned short* csr_src = (unsigned short*)alloc((size_t)ET * sizeof(unsigned short));
  f16* wt = (f16*)alloc(49152 * sizeof(f16));
  f16* h1 = (f16*)alloc((size_t)NN * 128 * sizeof(f16));
  float* as1 = (float*)alloc((size_t)NN * 4 * sizeof(float));
  float* ad1 = (float*)alloc((size_t)NN * 4 * sizeof(float));
  f16* out1h = (f16*)alloc((size_t)NN * 128 * sizeof(f16));
  f16* hh2 = h1;  // layer-2 features reuse h1 (dead after gat1)
  float* as2 = as1;
  float* ad2 = ad1;

  const int* src = ei;
  const int* dst = ei + NE;

  hipLaunchKernelGGL(wprep_kernel, dim3(96), dim3(256), 0, stream, W1, W2, wt);
  hipLaunchKernelGGL(binit_kernel, dim3(1), dim3(256), 0, stream, bcursor);
  hipLaunchKernelGGL(bpart_kernel, dim3((NE + CCHUNK - 1) / CCHUNK), dim3(256), 0,
                     stream, src, dst, bcursor, ebuf);
  hipLaunchKernelGGL(cscan_kernel, dim3(1), dim3(256), 0, stream, bcursor, csr_base,
                     rowptr);
  hipLaunchKernelGGL(bcsr_kernel, dim3(NBUK), dim3(256), 0, stream, ebuf, bcursor,
                     csr_base, rowptr, csr_src);

  int rbks = (NN + 63) / 64;
  hipLaunchKernelGGL((mfma_gemm_kernel<128, true>), dim3(rbks, 2), dim3(256), 0, stream,
                     x, wt, wt + 16384, att_s1, att_d1, h1, as1, ad1, NN);
  hipLaunchKernelGGL(gat1_kernel, dim3((NN + 3) / 4), dim3(256), 0, stream, rowptr,
                     csr_src, h1, as1, ad1, b1, out1h, NN);

  hipLaunchKernelGGL((mfma_gemm_kernel<64, false>), dim3(rbks, 1), dim3(256), 0, stream,
                     out1h, wt + 32768, wt + 40960, att_s2, att_d2, hh2, as2, ad2, NN);
  hipLaunchKernelGGL(gat2_kernel, dim3((NN + 3) / 4), dim3(256), 0, stream, rowptr,
                     csr_src, hh2, as2, ad2, b2, out, NN);
}

// Round 10
// 126.412 us; speedup vs baseline: 4.8061x; 1.0594x over previous
//
#include <hip/hip_runtime.h>

#define NN 50000
#define NE 800000
#define ET (NE + NN)
#define SLOPE 0.2f
#define GEPS 1e-16f
#define NBUK 196     // ceil(NN/256) dst-buckets of 256 nodes
#define BCAP 8192    // per-bucket edge capacity (avg 4080, max ~4400)
#define CCHUNK 2048  // edges per partition block
#define NPB ((NE + CCHUNK - 1) / CCHUNK)  // 391 partition blocks
#define RBKS ((NN + 63) / 64)             // 782 gemm row-blocks

typedef _Float16 f16;
typedef f16 f16x4 __attribute__((ext_vector_type(4)));
typedef f16 f16x8 __attribute__((ext_vector_type(8)));
typedef float f32x4 __attribute__((ext_vector_type(4)));

// ---- W prep (hi/lo f16 split, transposed) + bucket cursor init ----
__global__ __launch_bounds__(256) void wprep_kernel(const float* __restrict__ W1,
                                                    const float* __restrict__ W2,
                                                    f16* __restrict__ wt,
                                                    int* __restrict__ bcursor) {
  int idx = blockIdx.x * 256 + threadIdx.x;
  if (idx < 16384) {
    int c = idx >> 7, k = idx & 127;
    float w = W1[k * 128 + c];
    f16 hi = (f16)w;
    f16 lo = (f16)(w - (float)hi);
    wt[c * 128 + k] = hi;
    wt[16384 + c * 128 + k] = lo;
  } else if (idx < 24576) {
    int i2 = idx - 16384;
    int c = i2 >> 7, k = i2 & 127;
    float w = W2[k * 64 + c];
    f16 hi = (f16)w;
    f16 lo = (f16)(w - (float)hi);
    wt[32768 + c * 128 + k] = hi;
    wt[40960 + c * 128 + k] = lo;
  } else if (idx - 24576 < NBUK) {
    int b = idx - 24576;
    bcursor[b] = b * BCAP;
  }
}

// ---- shared GEMM body: H(f16) = A(N x 128) @ W(128 x NC) + att dots ----
template <int NC, bool AF32>
__device__ __forceinline__ void gemm_body(
    f16* __restrict__ Ah, f16* __restrict__ Wh, f16* __restrict__ Wl,
    const void* __restrict__ Av, const f16* __restrict__ whi,
    const f16* __restrict__ wlo, const float* __restrict__ atts,
    const float* __restrict__ attd, f16* __restrict__ Hh,
    float* __restrict__ a_s, float* __restrict__ a_d, int N, int bx, int by,
    int tid) {
  constexpr int K = 128, BM = 64, KP = K + 8;
  const int row0 = bx * BM;
  const int col0 = by * 64;
  if (AF32) {
    const float* A = (const float*)Av;
#pragma unroll
    for (int j = 0; j < 8; ++j) {
      int idx = j * 256 + tid;
      int r = idx >> 5, col = (idx & 31) << 2;
      int gr = row0 + r;
      float4 v = make_float4(0.f, 0.f, 0.f, 0.f);
      if (gr < N) v = *(const float4*)((const float*)A + (size_t)gr * K + col);
      f16x4 hv = {(f16)v.x, (f16)v.y, (f16)v.z, (f16)v.w};
      *(f16x4*)&Ah[r * KP + col] = hv;
    }
  } else {
    const f16* A = (const f16*)Av;
#pragma unroll
    for (int j = 0; j < 4; ++j) {
      int idx = j * 256 + tid;
      int r = idx >> 4, col = (idx & 15) << 3;
      int gr = row0 + r;
      f16x8 v = {};
      if (gr < N) v = *(const f16x8*)(A + (size_t)gr * K + col);
      *(f16x8*)&Ah[r * KP + col] = v;
    }
  }
#pragma unroll
  for (int j = 0; j < 4; ++j) {
    int idx = j * 256 + tid;
    int r = idx >> 4, col = (idx & 15) << 3;
    *(f16x8*)&Wh[r * KP + col] =
        *(const f16x8*)(whi + (size_t)(col0 + r) * K + col);
    *(f16x8*)&Wl[r * KP + col] =
        *(const f16x8*)(wlo + (size_t)(col0 + r) * K + col);
  }
  __syncthreads();
  const int lane = tid & 63;
  const int w = tid >> 6;
  const int lr = lane & 15;
  const int lk = (lane >> 4) << 3;
  f32x4 acc[4];
#pragma unroll
  for (int cf = 0; cf < 4; ++cf) acc[cf] = (f32x4){0.f, 0.f, 0.f, 0.f};
  const f16* arow = Ah + (w * 16 + lr) * KP + lk;
  const f16* bhrow = Wh + lr * KP + lk;
  const f16* blrow = Wl + lr * KP + lk;
#pragma unroll
  for (int ks = 0; ks < 4; ++ks) {
    int k0 = ks * 32;
    f16x8 af = *(const f16x8*)(arow + k0);
#pragma unroll
    for (int cf = 0; cf < 4; ++cf) {
      f16x8 bh = *(const f16x8*)(bhrow + cf * 16 * KP + k0);
      f16x8 bl = *(const f16x8*)(blrow + cf * 16 * KP + k0);
      acc[cf] = __builtin_amdgcn_mfma_f32_16x16x32_f16(af, bh, acc[cf], 0, 0, 0);
      acc[cf] = __builtin_amdgcn_mfma_f32_16x16x32_f16(af, bl, acc[cf], 0, 0, 0);
    }
  }
  const int rbase = row0 + w * 16 + ((lane >> 4) << 2);
#pragma unroll
  for (int cf = 0; cf < 4; ++cf) {
    int col = col0 + cf * 16 + lr;
#pragma unroll
    for (int r4 = 0; r4 < 4; ++r4) {
      int gr = rbase + r4;
      if (gr < N) Hh[(size_t)gr * NC + col] = (f16)acc[cf][r4];
    }
  }
  float asc[4], adc[4];
#pragma unroll
  for (int cf = 0; cf < 4; ++cf) {
    asc[cf] = atts[col0 + cf * 16 + lr];
    adc[cf] = attd[col0 + cf * 16 + lr];
  }
  if (NC == 128) {
#pragma unroll
    for (int m = 0; m < 2; ++m) {
#pragma unroll
      for (int r4 = 0; r4 < 4; ++r4) {
        float sp = acc[2 * m][r4] * asc[2 * m] + acc[2 * m + 1][r4] * asc[2 * m + 1];
        float dp = acc[2 * m][r4] * adc[2 * m] + acc[2 * m + 1][r4] * adc[2 * m + 1];
        sp += __shfl_xor(sp, 1); sp += __shfl_xor(sp, 2);
        sp += __shfl_xor(sp, 4); sp += __shfl_xor(sp, 8);
        dp += __shfl_xor(dp, 1); dp += __shfl_xor(dp, 2);
        dp += __shfl_xor(dp, 4); dp += __shfl_xor(dp, 8);
        int gr = rbase + r4;
        if (lr == 0 && gr < N) {
          int hd = by * 2 + m;
          a_s[gr * 4 + hd] = sp;
          a_d[gr * 4 + hd] = dp;
        }
      }
    }
  } else {
#pragma unroll
    for (int r4 = 0; r4 < 4; ++r4) {
      float sp = acc[0][r4] * asc[0] + acc[1][r4] * asc[1] +
                 acc[2][r4] * asc[2] + acc[3][r4] * asc[3];
      float dp = acc[0][r4] * adc[0] + acc[1][r4] * adc[1] +
                 acc[2][r4] * adc[2] + acc[3][r4] * adc[3];
      sp += __shfl_xor(sp, 1); sp += __shfl_xor(sp, 2);
      sp += __shfl_xor(sp, 4); sp += __shfl_xor(sp, 8);
      dp += __shfl_xor(dp, 1); dp += __shfl_xor(dp, 2);
      dp += __shfl_xor(dp, 4); dp += __shfl_xor(dp, 8);
      int gr = rbase + r4;
      if (lr == 0 && gr < N) {
        a_s[gr] = sp;
        a_d[gr] = dp;
      }
    }
  }
}

// ---- fused: edge partition (blocks 0..NPB-1) || GEMM1+att (rest) ----
__global__ __launch_bounds__(256) void fused1_kernel(
    const int* __restrict__ src, const int* __restrict__ dst,
    int* __restrict__ bcursor, unsigned int* __restrict__ ebuf,
    const float* __restrict__ x, const f16* __restrict__ whi,
    const f16* __restrict__ wlo, const float* __restrict__ atts,
    const float* __restrict__ attd, f16* __restrict__ Hh,
    float* __restrict__ a_s, float* __restrict__ a_d, int N) {
  constexpr int KP = 136;
  __shared__ __align__(16) char smem[3 * 64 * KP * sizeof(f16)];
  int t = threadIdx.x;
  if (blockIdx.x < NPB) {
    int* cnt = (int*)smem;
    int* ofs = cnt + NBUK;
    int* lcur = ofs + NBUK;
    for (int i = t; i < NBUK; i += 256) {
      cnt[i] = 0;
      lcur[i] = 0;
    }
    __syncthreads();
    int base = blockIdx.x * CCHUNK;
    int nend = min(base + CCHUNK, NE);
    for (int i = base + t; i < nend; i += 256) atomicAdd(&cnt[dst[i] >> 8], 1);
    __syncthreads();
    for (int i = t; i < NBUK; i += 256)
      if (cnt[i] > 0) ofs[i] = atomicAdd(&bcursor[i], cnt[i]);
    __syncthreads();
    for (int i = base + t; i < nend; i += 256) {
      int d = dst[i];
      int s = src[i];
      int b = d >> 8;
      int p = ofs[b] + atomicAdd(&lcur[b], 1);
      ebuf[p] = ((unsigned)(d & 255) << 16) | (unsigned)s;
    }
  } else {
    int gb = blockIdx.x - NPB;
    int bx = (gb >= RBKS) ? gb - RBKS : gb;
    int by = (gb >= RBKS) ? 1 : 0;
    f16* Ah = (f16*)smem;
    f16* Wh = Ah + 64 * KP;
    f16* Wl = Wh + 64 * KP;
    gemm_body<128, true>(Ah, Wh, Wl, x, whi, wlo, atts, attd, Hh, a_s, a_d, N,
                         bx, by, t);
  }
}

// ---- standalone GEMM2 ----
template <int NC, bool AF32>
__global__ __launch_bounds__(256) void mfma_gemm_kernel(
    const void* __restrict__ Av, const f16* __restrict__ whi,
    const f16* __restrict__ wlo, const float* __restrict__ atts,
    const float* __restrict__ attd, f16* __restrict__ Hh,
    float* __restrict__ a_s, float* __restrict__ a_d, int N) {
  constexpr int KP = 136;
  __shared__ f16 Ah[64 * KP];
  __shared__ f16 Wh[64 * KP];
  __shared__ f16 Wl[64 * KP];
  gemm_body<NC, AF32>(Ah, Wh, Wl, Av, whi, wlo, atts, attd, Hh, a_s, a_d, N,
                      blockIdx.x, blockIdx.y, threadIdx.x);
}

// ---- per-bucket CSR build with integrated bucket-base scan ----
__global__ __launch_bounds__(256) void bcsr_kernel(
    const unsigned int* __restrict__ ebuf, const int* __restrict__ bcursor,
    int* __restrict__ rowptr, unsigned short* __restrict__ csr) {
  __shared__ int sc[256];
  __shared__ int deg[256];
  __shared__ int lcur[256];
  int b = blockIdx.x;
  int t = threadIdx.x;
  // scan all bucket sizes (edges + self-loops) to find this bucket's base
  int nodes_t = (t < NBUK) ? min(256, NN - t * 256) : 0;
  int v = (t < NBUK) ? (bcursor[t] - t * BCAP + nodes_t) : 0;
  sc[t] = v;
  __syncthreads();
  for (int off = 1; off < 256; off <<= 1) {
    int u = (t >= off) ? sc[t - off] : 0;
    __syncthreads();
    sc[t] += u;
    __syncthreads();
  }
  int cb = (b > 0) ? sc[b - 1] : 0;
  if (b == NBUK - 1 && t == 0) rowptr[NN] = ET;
  int ebase = b * BCAP;
  int count = bcursor[b] - ebase;
  int n0 = b * 256;
  int nodes = min(256, NN - n0);
  deg[t] = 0;
  __syncthreads();
  for (int i = t; i < count; i += 256) atomicAdd(&deg[ebuf[ebase + i] >> 16], 1);
  __syncthreads();
  int myv = (t < nodes) ? (deg[t] + 1) : 0;  // +1 self-loop
  __syncthreads();
  deg[t] = myv;
  __syncthreads();
  for (int off = 1; off < 256; off <<= 1) {
    int u = (t >= off) ? deg[t - off] : 0;
    __syncthreads();
    deg[t] += u;
    __syncthreads();
  }
  if (t < nodes) {
    int excl = cb + deg[t] - myv;
    rowptr[n0 + t] = excl;
    csr[excl] = (unsigned short)(n0 + t);  // self-loop in slot 0
    lcur[t] = excl + 1;
  }
  __syncthreads();
  for (int i = t; i < count; i += 256) {
    unsigned e = ebuf[ebase + i];
    int p = atomicAdd(&lcur[e >> 16], 1);
    csr[p] = (unsigned short)(e & 0xFFFFu);
  }
}

// ---------------- layer-1 aggregation: 16 lanes/edge, 4x unroll ----------------
__global__ __launch_bounds__(256) void gat1_kernel(
    const int* __restrict__ rowptr, const unsigned short* __restrict__ csr_src,
    const f16* __restrict__ h1, const float* __restrict__ as1,
    const float* __restrict__ ad1, const float* __restrict__ b1,
    f16* __restrict__ out1, int N) {
  int n = (blockIdx.x * 256 + threadIdx.x) >> 6;
  int l = threadIdx.x & 63;
  if (n >= N) return;
  int start = rowptr[n], end = rowptr[n + 1];
  int c = l & 15, q = l >> 4;  // lane c: channels 8c..8c+7; q: edge slot 0..3
  int hB = c >> 2;
  float ad_b = ad1[n * 4 + hB];
  float acc[8] = {0.f, 0.f, 0.f, 0.f, 0.f, 0.f, 0.f, 0.f};
  float z = 0.f;
  int e = start + q;
  for (; e + 12 < end; e += 16) {
    int s0 = csr_src[e];
    int s1 = csr_src[e + 4];
    int s2 = csr_src[e + 8];
    int s3 = csr_src[e + 12];
    float a0 = as1[s0 * 4 + hB] + ad_b;
    float a1 = as1[s1 * 4 + hB] + ad_b;
    float a2 = as1[s2 * 4 + hB] + ad_b;
    float a3 = as1[s3 * 4 + hB] + ad_b;
    f16x8 g0 = *(const f16x8*)(h1 + (size_t)s0 * 128 + 8 * c);
    f16x8 g1 = *(const f16x8*)(h1 + (size_t)s1 * 128 + 8 * c);
    f16x8 g2 = *(const f16x8*)(h1 + (size_t)s2 * 128 + 8 * c);
    f16x8 g3 = *(const f16x8*)(h1 + (size_t)s3 * 128 + 8 * c);
    a0 = (a0 > 0.f) ? a0 : SLOPE * a0;
    a1 = (a1 > 0.f) ? a1 : SLOPE * a1;
    a2 = (a2 > 0.f) ? a2 : SLOPE * a2;
    a3 = (a3 > 0.f) ? a3 : SLOPE * a3;
    float w0 = __expf(a0), w1 = __expf(a1), w2 = __expf(a2), w3 = __expf(a3);
#pragma unroll
    for (int j = 0; j < 8; ++j)
      acc[j] += w0 * (float)g0[j] + w1 * (float)g1[j] + w2 * (float)g2[j] +
                w3 * (float)g3[j];
    z += w0 + w1 + w2 + w3;
  }
  for (; e < end; e += 4) {
    int s = csr_src[e];
    float a = as1[s * 4 + hB] + ad_b;
    a = (a > 0.f) ? a : SLOPE * a;
    float w = __expf(a);
    f16x8 g = *(const f16x8*)(h1 + (size_t)s * 128 + 8 * c);
#pragma unroll
    for (int j = 0; j < 8; ++j) acc[j] += w * (float)g[j];
    z += w;
  }
#pragma unroll
  for (int j = 0; j < 8; ++j) {
    acc[j] += __shfl_xor(acc[j], 16);
    acc[j] += __shfl_xor(acc[j], 32);
  }
  z += __shfl_xor(z, 16);
  z += __shfl_xor(z, 32);
  if (q == 0) {
    float inv = 1.f / (z + GEPS);
    float4 bb0 = *(const float4*)(b1 + 8 * c);
    float4 bb1 = *(const float4*)(b1 + 8 * c + 4);
    f16x8 o;
    o[0] = (f16)fmaxf(acc[0] * inv + bb0.x, 0.f);
    o[1] = (f16)fmaxf(acc[1] * inv + bb0.y, 0.f);
    o[2] = (f16)fmaxf(acc[2] * inv + bb0.z, 0.f);
    o[3] = (f16)fmaxf(acc[3] * inv + bb0.w, 0.f);
    o[4] = (f16)fmaxf(acc[4] * inv + bb1.x, 0.f);
    o[5] = (f16)fmaxf(acc[5] * inv + bb1.y, 0.f);
    o[6] = (f16)fmaxf(acc[6] * inv + bb1.z, 0.f);
    o[7] = (f16)fmaxf(acc[7] * inv + bb1.w, 0.f);
    *(f16x8*)(out1 + (size_t)n * 128 + 8 * c) = o;
  }
}

// ---------------- layer-2 aggregation: 8 lanes/edge, 4x unroll ----------------
__global__ __launch_bounds__(256) void gat2_kernel(
    const int* __restrict__ rowptr, const unsigned short* __restrict__ csr_src,
    const f16* __restrict__ h2, const float* __restrict__ as2,
    const float* __restrict__ ad2, const float* __restrict__ b2,
    float* __restrict__ out, int N) {
  int n = (blockIdx.x * 256 + threadIdx.x) >> 6;
  int l = threadIdx.x & 63;
  if (n >= N) return;
  int start = rowptr[n], end = rowptr[n + 1];
  int c = l & 7, q = l >> 3;  // lane c: channels 8c..8c+7; q: edge slot 0..7
  float ad = ad2[n];
  float acc[8] = {0.f, 0.f, 0.f, 0.f, 0.f, 0.f, 0.f, 0.f};
  float z = 0.f;
  int e = start + q;
  for (; e + 24 < end; e += 32) {
    int s0 = csr_src[e];
    int s1 = csr_src[e + 8];
    int s2 = csr_src[e + 16];
    int s3 = csr_src[e + 24];
    float a0 = as2[s0] + ad;
    float a1 = as2[s1] + ad;
    float a2 = as2[s2] + ad;
    float a3 = as2[s3] + ad;
    f16x8 g0 = *(const f16x8*)(h2 + (size_t)s0 * 64 + 8 * c);
    f16x8 g1 = *(const f16x8*)(h2 + (size_t)s1 * 64 + 8 * c);
    f16x8 g2 = *(const f16x8*)(h2 + (size_t)s2 * 64 + 8 * c);
    f16x8 g3 = *(const f16x8*)(h2 + (size_t)s3 * 64 + 8 * c);
    a0 = (a0 > 0.f) ? a0 : SLOPE * a0;
    a1 = (a1 > 0.f) ? a1 : SLOPE * a1;
    a2 = (a2 > 0.f) ? a2 : SLOPE * a2;
    a3 = (a3 > 0.f) ? a3 : SLOPE * a3;
    float w0 = __expf(a0), w1 = __expf(a1), w2 = __expf(a2), w3 = __expf(a3);
#pragma unroll
    for (int j = 0; j < 8; ++j)
      acc[j] += w0 * (float)g0[j] + w1 * (float)g1[j] + w2 * (float)g2[j] +
                w3 * (float)g3[j];
    z += w0 + w1 + w2 + w3;
  }
  for (; e < end; e += 8) {
    int s = csr_src[e];
    float a = as2[s] + ad;
    a = (a > 0.f) ? a : SLOPE * a;
    float w = __expf(a);
    f16x8 g = *(const f16x8*)(h2 + (size_t)s * 64 + 8 * c);
#pragma unroll
    for (int j = 0; j < 8; ++j) acc[j] += w * (float)g[j];
    z += w;
  }
#pragma unroll
  for (int j = 0; j < 8; ++j) {
    acc[j] += __shfl_xor(acc[j], 8);
    acc[j] += __shfl_xor(acc[j], 16);
    acc[j] += __shfl_xor(acc[j], 32);
  }
  z += __shfl_xor(z, 8);
  z += __shfl_xor(z, 16);
  z += __shfl_xor(z, 32);
  if (q == 0) {
    float inv = 1.f / (z + GEPS);
    float4 bb0 = *(const float4*)(b2 + 8 * c);
    float4 bb1 = *(const float4*)(b2 + 8 * c + 4);
    float4 o0, o1;
    o0.x = fmaxf(acc[0] * inv + bb0.x, 0.f);
    o0.y = fmaxf(acc[1] * inv + bb0.y, 0.f);
    o0.z = fmaxf(acc[2] * inv + bb0.z, 0.f);
    o0.w = fmaxf(acc[3] * inv + bb0.w, 0.f);
    o1.x = fmaxf(acc[4] * inv + bb1.x, 0.f);
    o1.y = fmaxf(acc[5] * inv + bb1.y, 0.f);
    o1.z = fmaxf(acc[6] * inv + bb1.z, 0.f);
    o1.w = fmaxf(acc[7] * inv + bb1.w, 0.f);
    *(float4*)(out + (size_t)n * 64 + 8 * c) = o0;
    *(float4*)(out + (size_t)n * 64 + 8 * c + 4) = o1;
  }
}

extern "C" void kernel_launch(void* const* d_in, const int* in_sizes, int n_in,
                              void* d_out, int out_size, void* d_ws, size_t ws_size,
                              hipStream_t stream) {
  const float* x = (const float*)d_in[0];
  const int* ei = (const int*)d_in[1];
  const float* W1 = (const float*)d_in[2];
  const float* att_s1 = (const float*)d_in[3];
  const float* att_d1 = (const float*)d_in[4];
  const float* b1 = (const float*)d_in[5];
  const float* W2 = (const float*)d_in[6];
  const float* att_s2 = (const float*)d_in[7];
  const float* att_d2 = (const float*)d_in[8];
  const float* b2 = (const float*)d_in[9];
  float* out = (float*)d_out;

  char* ws = (char*)d_ws;
  size_t off = 0;
  auto alloc = [&](size_t bytes) {
    off = (off + 255) & ~(size_t)255;
    void* p = ws + off;
    off += bytes;
    return p;
  };
  int* bcursor = (int*)alloc(NBUK * sizeof(int));
  unsigned int* ebuf = (unsigned int*)alloc((size_t)NBUK * BCAP * sizeof(unsigned int));
  int* rowptr = (int*)alloc((NN + 1) * sizeof(int));
  unsigned short* csr_src = (unsigned short*)alloc((size_t)ET * sizeof(unsigned short));
  f16* wt = (f16*)alloc(49152 * sizeof(f16));
  f16* h1 = (f16*)alloc((size_t)NN * 128 * sizeof(f16));
  float* as1 = (float*)alloc((size_t)NN * 4 * sizeof(float));
  float* ad1 = (float*)alloc((size_t)NN * 4 * sizeof(float));
  f16* out1h = (f16*)alloc((size_t)NN * 128 * sizeof(f16));
  f16* hh2 = h1;  // layer-2 features reuse h1 (dead after gat1)
  float* as2 = as1;
  float* ad2 = ad1;

  const int* src = ei;
  const int* dst = ei + NE;

  hipLaunchKernelGGL(wprep_kernel, dim3(97), dim3(256), 0, stream, W1, W2, wt,
                     bcursor);
  hipLaunchKernelGGL(fused1_kernel, dim3(NPB + 2 * RBKS), dim3(256), 0, stream, src,
                     dst, bcursor, ebuf, x, wt, wt + 16384, att_s1, att_d1, h1, as1,
                     ad1, NN);
  hipLaunchKernelGGL(bcsr_kernel, dim3(NBUK), dim3(256), 0, stream, ebuf, bcursor,
                     rowptr, csr_src);
  hipLaunchKernelGGL(gat1_kernel, dim3((NN + 3) / 4), dim3(256), 0, stream, rowptr,
                     csr_src, h1, as1, ad1, b1, out1h, NN);
  hipLaunchKernelGGL((mfma_gemm_kernel<64, false>), dim3(RBKS, 1), dim3(256), 0,
                     stream, out1h, wt + 32768, wt + 40960, att_s2, att_d2, hh2, as2,
                     ad2, NN);
  hipLaunchKernelGGL(gat2_kernel, dim3((NN + 3) / 4), dim3(256), 0, stream, rowptr,
                     csr_src, hh2, as2, ad2, b2, out, NN);
}